// Round 11
// baseline (278.083 us; speedup 1.0000x reference)
//
#include <hip/hip_runtime.h>
#include <hip/hip_bf16.h>

#define HID 256
#define HID2 512
#define NPG 200
#define LN_EPS 1e-5f

typedef float f32x4 __attribute__((ext_vector_type(4)));
typedef short s16x8 __attribute__((ext_vector_type(8)));
typedef unsigned short ushort_t;

// round-to-nearest-even float -> bf16 bit pattern
__device__ __forceinline__ ushort_t f2bf_rne(float x) {
    union { float f; unsigned int u; } c; c.f = x;
    unsigned int u = c.u;
    return (ushort_t)((u + 0x7fffu + ((u >> 16) & 1u)) >> 16);
}
__device__ __forceinline__ float bf2f(ushort_t h) {
    union { unsigned int u; float f; } c; c.u = ((unsigned int)h) << 16;
    return c.f;
}

// ---------------------------------------------------------------------------
// K_w1: W1[256][512] -> fragment-major bf16 hi/lo buffers.
// Layout: w1f[(((tile*8 + kq)*64) + lane)*8 + j], lane = gq*16+lc,
// holding W1[k][col] with col = tile*16+lc, k = kq*32+gq*8+j.
// ---------------------------------------------------------------------------
__global__ __launch_bounds__(256)
void w1_prep_kernel(const float* __restrict__ W1,
                    ushort_t* __restrict__ w1h, ushort_t* __restrict__ w1l)
{
    const int col = blockIdx.x;    // 0..511
    const int k   = threadIdx.x;   // 0..255
    const float v = W1[(size_t)k * HID2 + col];
    const ushort_t hi = f2bf_rne(v);
    const ushort_t lo = f2bf_rne(v - bf2f(hi));
    const int tile = col >> 4, lc = col & 15;
    const int kq = k >> 5, gq = (k >> 3) & 3, j = k & 7;
    const size_t idx = ((((size_t)tile << 3) + kq) * 64 + (gq << 4) + lc) * 8 + j;
    w1h[idx] = hi;
    w1l[idx] = lo;
}

// ---------------------------------------------------------------------------
// K1: fused  x = h + g[batch];  z = x@W1 + b1;  LayerNorm; ReLU; logit = z.W2+b2
// bf16x3 MFMA, fully-unrolled K-loop with PER-WAVE K-ORDER ROTATION
// (kq = (w+i)&7) to de-phase-lock the 16 waves/CU, + s_setprio around MFMA.
// ---------------------------------------------------------------------------
__global__ __launch_bounds__(512, 4)
void mlp_logits_mfma(const float* __restrict__ h, const float* __restrict__ g,
                     const int* __restrict__ batch,
                     const ushort_t* __restrict__ w1h, const ushort_t* __restrict__ w1l,
                     const float* __restrict__ b1,
                     const float* __restrict__ lng, const float* __restrict__ lnb,
                     const float* __restrict__ W2, const float* __restrict__ b2,
                     float* __restrict__ logits)
{
    __shared__ ushort_t xsh[64 * 256];   // 32 KB, swizzled
    __shared__ ushort_t xsl[64 * 256];   // 32 KB, swizzled
    __shared__ float prm[4 * 512];       // b1 | lng | lnb | W2
    __shared__ float redS1[8][64];
    __shared__ float redS2[8][64];
    __shared__ float redT[8][64];
    __shared__ float muv[64], rsv[64];

    const int tid  = threadIdx.x;
    const int row0 = blockIdx.x * 64;

    // ---- params -> LDS ----
    {
        const int c = tid;               // 0..511
        prm[c]        = b1[c];
        prm[512 + c]  = lng[c];
        prm[1024 + c] = lnb[c];
        prm[1536 + c] = W2[c];
    }

    // ---- stage x = h + g[batch], split to bf16 hi/lo in swizzled LDS ----
    #pragma unroll
    for (int i = 0; i < 4; ++i) {
        const int ci = tid + (i << 9);      // 0..2047
        const int r  = ci >> 5;             // 0..63
        const int kc = (ci & 31) << 3;      // 0..248
        const int grow = row0 + r;
        const int gb   = batch[grow];
        const f32x4* hp = reinterpret_cast<const f32x4*>(h + (size_t)grow * HID + kc);
        const f32x4* gp = reinterpret_cast<const f32x4*>(g + (size_t)gb   * HID + kc);
        const f32x4 h0 = __builtin_nontemporal_load(hp);
        const f32x4 h1 = __builtin_nontemporal_load(hp + 1);
        const f32x4 g0 = gp[0], g1 = gp[1];
        float xv[8] = { h0.x + g0.x, h0.y + g0.y, h0.z + g0.z, h0.w + g0.w,
                        h1.x + g1.x, h1.y + g1.y, h1.z + g1.z, h1.w + g1.w };
        ushort_t hh[8], ll[8];
        #pragma unroll
        for (int j = 0; j < 8; ++j) {
            const ushort_t hi = f2bf_rne(xv[j]);
            hh[j] = hi;
            ll[j] = f2bf_rne(xv[j] - bf2f(hi));
        }
        int byte_off = r * 512 + (kc << 1);
        byte_off ^= (r & 7) << 4;
        *reinterpret_cast<s16x8*>(reinterpret_cast<char*>(xsh) + byte_off) =
            *reinterpret_cast<const s16x8*>(hh);
        *reinterpret_cast<s16x8*>(reinterpret_cast<char*>(xsl) + byte_off) =
            *reinterpret_cast<const s16x8*>(ll);
    }
    __syncthreads();

    const int w  = tid >> 6;       // wave 0..7 -> cols w*64..+63
    const int l  = tid & 63;
    const int lc = l & 15;         // A-row / B-col / C-col index within tile
    const int gq = l >> 4;         // k-chunk group 0..3 (and C row group)
    const int wcol0 = w << 6;

    f32x4 acc[4][4];               // [rt][ct]
    #pragma unroll
    for (int rt = 0; rt < 4; ++rt)
        #pragma unroll
        for (int ct = 0; ct < 4; ++ct) acc[rt][ct] = (f32x4){0.f, 0.f, 0.f, 0.f};

    // fragment-major B base for this wave+lane: tiles w*4..w*4+3
    const ushort_t* bfh = w1h + (((size_t)w << 2) << 3) * 512 + (size_t)l * 8;
    const ushort_t* bfl = w1l + (((size_t)w << 2) << 3) * 512 + (size_t)l * 8;

    #pragma unroll
    for (int i = 0; i < 8; ++i) {
        const int kq = (w + i) & 7;     // per-wave rotated K order (uniform addr)
        // B fragments: coalesced 1KB wave loads
        s16x8 bh[4], bl[4];
        #pragma unroll
        for (int ct = 0; ct < 4; ++ct) {
            const size_t foff = (size_t)((ct << 3) + kq) * 512;
            bh[ct] = *reinterpret_cast<const s16x8*>(bfh + foff);
            bl[ct] = *reinterpret_cast<const s16x8*>(bfl + foff);
        }
        // A fragments: row = rt*16 + lc, k = kq*32 + gq*8
        s16x8 ah[4], al[4];
        #pragma unroll
        for (int rt = 0; rt < 4; ++rt) {
            const int arow = (rt << 4) | lc;
            int abyte = arow * 512 + (((kq << 5) + (gq << 3)) << 1);
            abyte ^= (arow & 7) << 4;
            ah[rt] = *reinterpret_cast<const s16x8*>(
                         reinterpret_cast<const char*>(xsh) + abyte);
            al[rt] = *reinterpret_cast<const s16x8*>(
                         reinterpret_cast<const char*>(xsl) + abyte);
        }
        // term-outer MFMA order: 16 independent accs between same-acc reuse
        __builtin_amdgcn_s_setprio(1);
        #pragma unroll
        for (int ct = 0; ct < 4; ++ct)
            #pragma unroll
            for (int rt = 0; rt < 4; ++rt)
                acc[rt][ct] = __builtin_amdgcn_mfma_f32_16x16x32_bf16(ah[rt], bh[ct], acc[rt][ct], 0, 0, 0);
        #pragma unroll
        for (int ct = 0; ct < 4; ++ct)
            #pragma unroll
            for (int rt = 0; rt < 4; ++rt)
                acc[rt][ct] = __builtin_amdgcn_mfma_f32_16x16x32_bf16(al[rt], bh[ct], acc[rt][ct], 0, 0, 0);
        #pragma unroll
        for (int ct = 0; ct < 4; ++ct)
            #pragma unroll
            for (int rt = 0; rt < 4; ++rt)
                acc[rt][ct] = __builtin_amdgcn_mfma_f32_16x16x32_bf16(ah[rt], bl[ct], acc[rt][ct], 0, 0, 0);
        __builtin_amdgcn_s_setprio(0);
    }

    // ---- epilogue ----
    // C-layout per (rt,ct) tile: lane holds col wcol0+ct*16+lc, row rt*16+gq*4+reg.
    #pragma unroll
    for (int rt = 0; rt < 4; ++rt) {
        float s1[4] = {0.f, 0.f, 0.f, 0.f};
        float s2[4] = {0.f, 0.f, 0.f, 0.f};
        #pragma unroll
        for (int ct = 0; ct < 4; ++ct) {
            const float bb = prm[wcol0 + (ct << 4) + lc];
            #pragma unroll
            for (int reg = 0; reg < 4; ++reg) {
                const float v = acc[rt][ct][reg] + bb;
                acc[rt][ct][reg] = v;
                s1[reg] += v;
                s2[reg] = fmaf(v, v, s2[reg]);
            }
        }
        #pragma unroll
        for (int reg = 0; reg < 4; ++reg) {
            float a = s1[reg], q = s2[reg];
            a += __shfl_xor(a, 1); q += __shfl_xor(q, 1);
            a += __shfl_xor(a, 2); q += __shfl_xor(q, 2);
            a += __shfl_xor(a, 4); q += __shfl_xor(q, 4);
            a += __shfl_xor(a, 8); q += __shfl_xor(q, 8);
            if (lc == 0) {
                const int row = (rt << 4) + (gq << 2) + reg;
                redS1[w][row] = a;
                redS2[w][row] = q;
            }
        }
    }
    __syncthreads();

    if (tid < 64) {
        float S1 = 0.f, S2 = 0.f;
        #pragma unroll
        for (int i = 0; i < 8; ++i) { S1 += redS1[i][tid]; S2 += redS2[i][tid]; }
        const float mu = S1 * (1.0f / HID2);
        const float var = S2 * (1.0f / HID2) - mu * mu;
        muv[tid] = mu;
        rsv[tid] = rsqrtf(var + LN_EPS);
    }
    __syncthreads();

    #pragma unroll
    for (int rt = 0; rt < 4; ++rt) {
        float tpart[4] = {0.f, 0.f, 0.f, 0.f};
        float mus[4], rss[4];
        #pragma unroll
        for (int reg = 0; reg < 4; ++reg) {
            const int row = (rt << 4) + (gq << 2) + reg;
            mus[reg] = muv[row];
            rss[reg] = rsv[row];
        }
        #pragma unroll
        for (int ct = 0; ct < 4; ++ct) {
            const int c = wcol0 + (ct << 4) + lc;
            const float lg = prm[512 + c], lb = prm[1024 + c], w2 = prm[1536 + c];
            #pragma unroll
            for (int reg = 0; reg < 4; ++reg) {
                float zn = (acc[rt][ct][reg] - mus[reg]) * rss[reg] * lg + lb;
                zn = fmaxf(zn, 0.f);
                tpart[reg] = fmaf(zn, w2, tpart[reg]);
            }
        }
        #pragma unroll
        for (int reg = 0; reg < 4; ++reg) {
            float t = tpart[reg];
            t += __shfl_xor(t, 1); t += __shfl_xor(t, 2);
            t += __shfl_xor(t, 4); t += __shfl_xor(t, 8);
            if (lc == 0) redT[w][(rt << 4) + (gq << 2) + reg] = t;
        }
    }
    __syncthreads();

    if (tid < 64) {
        float t = 0.f;
        #pragma unroll
        for (int i = 0; i < 8; ++i) t += redT[i][tid];
        logits[row0 + tid] = t + b2[0];
    }
}

// ---------------------------------------------------------------------------
// K2: per-graph softmax + seed selection (first-index max of node_prob).
// ---------------------------------------------------------------------------
__global__ __launch_bounds__(256)
void softmax_seed_kernel(const float* __restrict__ logits,
                         float* __restrict__ out_prob,
                         unsigned char* __restrict__ nm)
{
    const int gid  = blockIdx.x;
    const int tid  = threadIdx.x;
    const int node = gid * NPG + tid;
    const bool act = tid < NPG;

    __shared__ float redf[4];
    __shared__ int   redi[4];

    float l = act ? logits[node] : -INFINITY;

    float m = l;
    #pragma unroll
    for (int off = 32; off >= 1; off >>= 1) m = fmaxf(m, __shfl_xor(m, off));
    if ((tid & 63) == 0) redf[tid >> 6] = m;
    __syncthreads();
    const float bm = fmaxf(fmaxf(redf[0], redf[1]), fmaxf(redf[2], redf[3]));
    __syncthreads();

    const float e = act ? expf(l - bm) : 0.0f;
    float s = e;
    #pragma unroll
    for (int off = 32; off >= 1; off >>= 1) s += __shfl_xor(s, off);
    if ((tid & 63) == 0) redf[tid >> 6] = s;
    __syncthreads();
    const float bs = redf[0] + redf[1] + redf[2] + redf[3];
    __syncthreads();

    const float p = act ? e / bs : -1.0f;
    if (act) out_prob[node] = p;

    float pm = p;
    #pragma unroll
    for (int off = 32; off >= 1; off >>= 1) pm = fmaxf(pm, __shfl_xor(pm, off));
    if ((tid & 63) == 0) redf[tid >> 6] = pm;
    __syncthreads();
    const float bpm = fmaxf(fmaxf(redf[0], redf[1]), fmaxf(redf[2], redf[3]));

    int c = (act && p >= bpm) ? node : 0x7FFFFFFF;
    #pragma unroll
    for (int off = 32; off >= 1; off >>= 1) c = min(c, __shfl_xor(c, off));
    if ((tid & 63) == 0) redi[tid >> 6] = c;
    __syncthreads();
    if (tid == 0) {
        const int seed = min(min(redi[0], redi[1]), min(redi[2], redi[3]));
        nm[seed] = 1;   // level 1
    }
}

// ---------------------------------------------------------------------------
// K3/K4: one synchronous BFS hop (expand target -> source), level-tagged.
// 4 edges/thread, unconditional int4 src+dst loads (coalesced streams).
// ---------------------------------------------------------------------------
__global__ __launch_bounds__(256)
void bfs_pass_kernel(const int* __restrict__ ei, unsigned char* __restrict__ nm,
                     const int E, const int maxlvl, const int newlvl)
{
    const int e = (blockIdx.x * blockDim.x + threadIdx.x) << 2;
    if (e >= E) return;
    const int4 s4 = *reinterpret_cast<const int4*>(ei + e);
    const int4 d4 = *reinterpret_cast<const int4*>(ei + E + e);
    #pragma unroll
    for (int j = 0; j < 4; ++j) {
        const int d = (j == 0) ? d4.x : (j == 1) ? d4.y : (j == 2) ? d4.z : d4.w;
        const int lv = nm[d];
        if (lv >= 1 && lv <= maxlvl) {
            const int s = (j == 0) ? s4.x : (j == 1) ? s4.y : (j == 2) ? s4.z : s4.w;
            if (nm[s] == 0) nm[s] = (unsigned char)newlvl;
        }
    }
}

// ---------------------------------------------------------------------------
// K5: edge outputs + node-mask scatter (float32 outputs), 4 edges/thread.
// ---------------------------------------------------------------------------
__global__ __launch_bounds__(256)
void edge_out_kernel(const int* __restrict__ ei, const float* __restrict__ logits,
                     const unsigned char* __restrict__ nm,
                     float* __restrict__ out_ew,
                     float* __restrict__ out_em,
                     unsigned char* __restrict__ nodemask, const int E)
{
    const int e = (blockIdx.x * blockDim.x + threadIdx.x) << 2;
    if (e >= E) return;
    const int4 s4 = *reinterpret_cast<const int4*>(ei + e);
    const int4 d4 = *reinterpret_cast<const int4*>(ei + E + e);
    f32x4 ew, em;
    #pragma unroll
    for (int j = 0; j < 4; ++j) {
        const int s = (j == 0) ? s4.x : (j == 1) ? s4.y : (j == 2) ? s4.z : s4.w;
        const int d = (j == 0) ? d4.x : (j == 1) ? d4.y : (j == 2) ? d4.z : d4.w;
        ew[j] = logits[s] + logits[d];
        const bool m = (nm[s] != 0) && (nm[d] != 0);
        em[j] = m ? 1.0f : 0.0f;
        if (m) { nodemask[s] = 1; nodemask[d] = 1; }
    }
    *reinterpret_cast<f32x4*>(out_ew + e) = ew;
    *reinterpret_cast<f32x4*>(out_em + e) = em;
}

// ---------------------------------------------------------------------------
// K6: node_mask -> float32 output, 4 nodes/thread.
// ---------------------------------------------------------------------------
__global__ __launch_bounds__(256)
void node_mask_kernel(const unsigned char* __restrict__ nodemask,
                      float* __restrict__ out_nm, const int N)
{
    const int i = (blockIdx.x * blockDim.x + threadIdx.x) << 2;
    if (i >= N) return;
    const uchar4 m4 = *reinterpret_cast<const uchar4*>(nodemask + i);
    f32x4 o;
    o[0] = m4.x ? 1.0f : 0.0f;
    o[1] = m4.y ? 1.0f : 0.0f;
    o[2] = m4.z ? 1.0f : 0.0f;
    o[3] = m4.w ? 1.0f : 0.0f;
    *reinterpret_cast<f32x4*>(out_nm + i) = o;
}

// ---------------------------------------------------------------------------
// K0: zero nm + nodemask scratch
// ---------------------------------------------------------------------------
__global__ __launch_bounds__(256)
void zero_ws_kernel(uint4* __restrict__ p, const int n16)
{
    const int i = blockIdx.x * blockDim.x + threadIdx.x;
    if (i < n16) p[i] = make_uint4(0u, 0u, 0u, 0u);
}

extern "C" void kernel_launch(void* const* d_in, const int* in_sizes, int n_in,
                              void* d_out, int out_size, void* d_ws, size_t ws_size,
                              hipStream_t stream)
{
    const float* h     = (const float*)d_in[0];
    const float* g     = (const float*)d_in[1];
    const int*   batch = (const int*)d_in[2];
    const int*   ei    = (const int*)d_in[3];
    const float* W1    = (const float*)d_in[4];
    const float* b1    = (const float*)d_in[5];
    const float* lng   = (const float*)d_in[6];
    const float* lnb   = (const float*)d_in[7];
    const float* W2    = (const float*)d_in[8];
    const float* b2    = (const float*)d_in[9];

    const int N = in_sizes[2];
    const int E = in_sizes[3] / 2;

    float* out        = (float*)d_out;
    float* out_prob   = out;                                  // [N]
    float* out_ew     = out + N;                              // [E]
    float* out_em     = out + (size_t)N + E;                  // [E]
    float* out_nmask  = out + (size_t)N + 2 * (size_t)E;      // [N]

    // workspace layout
    char* ws = (char*)d_ws;
    float*         logits   = (float*)ws;                               // N*4
    ushort_t*      w1h      = (ushort_t*)(ws + (size_t)N * 4);          // 512*256*2
    ushort_t*      w1l      = (ushort_t*)(ws + (size_t)N * 4 + 262144);
    unsigned char* nm       = (unsigned char*)(ws + (size_t)N * 4 + 524288);
    unsigned char* nodemask = nm + N;

    // zero nm + nodemask (2N bytes, 16B aligned)
    const int n16 = (2 * N) / 16;
    zero_ws_kernel<<<(n16 + 255) / 256, 256, 0, stream>>>((uint4*)nm, n16);

    w1_prep_kernel<<<HID2, HID, 0, stream>>>(W1, w1h, w1l);

    mlp_logits_mfma<<<N / 64, 512, 0, stream>>>(h, g, batch, w1h, w1l,
                                                b1, lng, lnb, W2, b2, logits);
    softmax_seed_kernel<<<N / NPG, 256, 0, stream>>>(logits, out_prob, nm);
    bfs_pass_kernel<<<(E / 4 + 255) / 256, 256, 0, stream>>>(ei, nm, E, 1, 2);
    bfs_pass_kernel<<<(E / 4 + 255) / 256, 256, 0, stream>>>(ei, nm, E, 2, 3);
    edge_out_kernel<<<(E / 4 + 255) / 256, 256, 0, stream>>>(ei, logits, nm,
                                                             out_ew, out_em,
                                                             nodemask, E);
    node_mask_kernel<<<(N / 4 + 255) / 256, 256, 0, stream>>>(nodemask, out_nmask, N);
}

// Round 12
// 232.815 us; speedup vs baseline: 1.1944x; 1.1944x over previous
//
#include <hip/hip_runtime.h>
#include <hip/hip_bf16.h>

#define HID 256
#define HID2 512
#define NPG 200
#define LN_EPS 1e-5f

typedef float f32x4 __attribute__((ext_vector_type(4)));
typedef short s16x8 __attribute__((ext_vector_type(8)));
typedef unsigned short ushort_t;

// round-to-nearest-even float -> bf16 bit pattern
__device__ __forceinline__ ushort_t f2bf_rne(float x) {
    union { float f; unsigned int u; } c; c.f = x;
    unsigned int u = c.u;
    return (ushort_t)((u + 0x7fffu + ((u >> 16) & 1u)) >> 16);
}
__device__ __forceinline__ float bf2f(ushort_t h) {
    union { unsigned int u; float f; } c; c.u = ((unsigned int)h) << 16;
    return c.f;
}

// ---------------------------------------------------------------------------
// K_w1: W1[256][512] -> fragment-major bf16 hi/lo buffers.
// Layout: w1f[(((tile*8 + kq)*64) + lane)*8 + j], lane = gq*16+lc,
// holding W1[k][col] with col = tile*16+lc, k = kq*32+gq*8+j.
// ---------------------------------------------------------------------------
__global__ __launch_bounds__(256)
void w1_prep_kernel(const float* __restrict__ W1,
                    ushort_t* __restrict__ w1h, ushort_t* __restrict__ w1l)
{
    const int col = blockIdx.x;    // 0..511
    const int k   = threadIdx.x;   // 0..255
    const float v = W1[(size_t)k * HID2 + col];
    const ushort_t hi = f2bf_rne(v);
    const ushort_t lo = f2bf_rne(v - bf2f(hi));
    const int tile = col >> 4, lc = col & 15;
    const int kq = k >> 5, gq = (k >> 3) & 3, j = k & 7;
    const size_t idx = ((((size_t)tile << 3) + kq) * 64 + (gq << 4) + lc) * 8 + j;
    w1h[idx] = hi;
    w1l[idx] = lo;
}

// ---------------------------------------------------------------------------
// K1: fused  x = h + g[batch];  z = x@W1 + b1;  LayerNorm; ReLU; logit = z.W2+b2
// bf16x3 MFMA, fully-unrolled STATIC K-loop (round-10 known-good: 132 us).
// 512 thr = 8 waves, BM=64; wave w owns cols w*64..+63. NT h loads.
// NOTE (twice-measured): runtime-dependent K offsets (lambda dbuf r9, wave
// rotation r11) spill to scratch (~150-900MB phantom traffic). Keep static.
// ---------------------------------------------------------------------------
__global__ __launch_bounds__(512, 4)
void mlp_logits_mfma(const float* __restrict__ h, const float* __restrict__ g,
                     const int* __restrict__ batch,
                     const ushort_t* __restrict__ w1h, const ushort_t* __restrict__ w1l,
                     const float* __restrict__ b1,
                     const float* __restrict__ lng, const float* __restrict__ lnb,
                     const float* __restrict__ W2, const float* __restrict__ b2,
                     float* __restrict__ logits)
{
    __shared__ ushort_t xsh[64 * 256];   // 32 KB, swizzled
    __shared__ ushort_t xsl[64 * 256];   // 32 KB, swizzled
    __shared__ float prm[4 * 512];       // b1 | lng | lnb | W2
    __shared__ float redS1[8][64];
    __shared__ float redS2[8][64];
    __shared__ float redT[8][64];
    __shared__ float muv[64], rsv[64];

    const int tid  = threadIdx.x;
    const int row0 = blockIdx.x * 64;

    // ---- params -> LDS ----
    {
        const int c = tid;               // 0..511
        prm[c]        = b1[c];
        prm[512 + c]  = lng[c];
        prm[1024 + c] = lnb[c];
        prm[1536 + c] = W2[c];
    }

    // ---- stage x = h + g[batch], split to bf16 hi/lo in swizzled LDS ----
    #pragma unroll
    for (int i = 0; i < 4; ++i) {
        const int ci = tid + (i << 9);      // 0..2047
        const int r  = ci >> 5;             // 0..63
        const int kc = (ci & 31) << 3;      // 0..248
        const int grow = row0 + r;
        const int gb   = batch[grow];
        const f32x4* hp = reinterpret_cast<const f32x4*>(h + (size_t)grow * HID + kc);
        const f32x4* gp = reinterpret_cast<const f32x4*>(g + (size_t)gb   * HID + kc);
        const f32x4 h0 = __builtin_nontemporal_load(hp);
        const f32x4 h1 = __builtin_nontemporal_load(hp + 1);
        const f32x4 g0 = gp[0], g1 = gp[1];
        float xv[8] = { h0.x + g0.x, h0.y + g0.y, h0.z + g0.z, h0.w + g0.w,
                        h1.x + g1.x, h1.y + g1.y, h1.z + g1.z, h1.w + g1.w };
        ushort_t hh[8], ll[8];
        #pragma unroll
        for (int j = 0; j < 8; ++j) {
            const ushort_t hi = f2bf_rne(xv[j]);
            hh[j] = hi;
            ll[j] = f2bf_rne(xv[j] - bf2f(hi));
        }
        int byte_off = r * 512 + (kc << 1);
        byte_off ^= (r & 7) << 4;
        *reinterpret_cast<s16x8*>(reinterpret_cast<char*>(xsh) + byte_off) =
            *reinterpret_cast<const s16x8*>(hh);
        *reinterpret_cast<s16x8*>(reinterpret_cast<char*>(xsl) + byte_off) =
            *reinterpret_cast<const s16x8*>(ll);
    }
    __syncthreads();

    const int w  = tid >> 6;       // wave 0..7 -> cols w*64..+63
    const int l  = tid & 63;
    const int lc = l & 15;         // A-row / B-col / C-col index within tile
    const int gq = l >> 4;         // k-chunk group 0..3 (and C row group)
    const int wcol0 = w << 6;

    f32x4 acc[4][4];               // [rt][ct]
    #pragma unroll
    for (int rt = 0; rt < 4; ++rt)
        #pragma unroll
        for (int ct = 0; ct < 4; ++ct) acc[rt][ct] = (f32x4){0.f, 0.f, 0.f, 0.f};

    // fragment-major B base for this wave+lane: tiles w*4..w*4+3
    const ushort_t* bfh = w1h + (((size_t)w << 2) << 3) * 512 + (size_t)l * 8;
    const ushort_t* bfl = w1l + (((size_t)w << 2) << 3) * 512 + (size_t)l * 8;

    #pragma unroll
    for (int kq = 0; kq < 8; ++kq) {
        // B fragments: coalesced 1KB wave loads, (ct*8+kq)*512 elements apart
        s16x8 bh[4], bl[4];
        #pragma unroll
        for (int ct = 0; ct < 4; ++ct) {
            const size_t foff = (size_t)((ct << 3) + kq) * 512;
            bh[ct] = *reinterpret_cast<const s16x8*>(bfh + foff);
            bl[ct] = *reinterpret_cast<const s16x8*>(bfl + foff);
        }
        // A fragments: row = rt*16 + lc, k = kq*32 + gq*8
        s16x8 ah[4], al[4];
        #pragma unroll
        for (int rt = 0; rt < 4; ++rt) {
            const int arow = (rt << 4) | lc;
            int abyte = arow * 512 + (((kq << 5) + (gq << 3)) << 1);
            abyte ^= (arow & 7) << 4;
            ah[rt] = *reinterpret_cast<const s16x8*>(
                         reinterpret_cast<const char*>(xsh) + abyte);
            al[rt] = *reinterpret_cast<const s16x8*>(
                         reinterpret_cast<const char*>(xsl) + abyte);
        }
        // term-outer MFMA order: 16 independent accs between same-acc reuse
        #pragma unroll
        for (int ct = 0; ct < 4; ++ct)
            #pragma unroll
            for (int rt = 0; rt < 4; ++rt)
                acc[rt][ct] = __builtin_amdgcn_mfma_f32_16x16x32_bf16(ah[rt], bh[ct], acc[rt][ct], 0, 0, 0);
        #pragma unroll
        for (int ct = 0; ct < 4; ++ct)
            #pragma unroll
            for (int rt = 0; rt < 4; ++rt)
                acc[rt][ct] = __builtin_amdgcn_mfma_f32_16x16x32_bf16(al[rt], bh[ct], acc[rt][ct], 0, 0, 0);
        #pragma unroll
        for (int ct = 0; ct < 4; ++ct)
            #pragma unroll
            for (int rt = 0; rt < 4; ++rt)
                acc[rt][ct] = __builtin_amdgcn_mfma_f32_16x16x32_bf16(ah[rt], bl[ct], acc[rt][ct], 0, 0, 0);
    }

    // ---- epilogue ----
    // C-layout per (rt,ct) tile: lane holds col wcol0+ct*16+lc, row rt*16+gq*4+reg.
    #pragma unroll
    for (int rt = 0; rt < 4; ++rt) {
        float s1[4] = {0.f, 0.f, 0.f, 0.f};
        float s2[4] = {0.f, 0.f, 0.f, 0.f};
        #pragma unroll
        for (int ct = 0; ct < 4; ++ct) {
            const float bb = prm[wcol0 + (ct << 4) + lc];
            #pragma unroll
            for (int reg = 0; reg < 4; ++reg) {
                const float v = acc[rt][ct][reg] + bb;
                acc[rt][ct][reg] = v;
                s1[reg] += v;
                s2[reg] = fmaf(v, v, s2[reg]);
            }
        }
        #pragma unroll
        for (int reg = 0; reg < 4; ++reg) {
            float a = s1[reg], q = s2[reg];
            a += __shfl_xor(a, 1); q += __shfl_xor(q, 1);
            a += __shfl_xor(a, 2); q += __shfl_xor(q, 2);
            a += __shfl_xor(a, 4); q += __shfl_xor(q, 4);
            a += __shfl_xor(a, 8); q += __shfl_xor(q, 8);
            if (lc == 0) {
                const int row = (rt << 4) + (gq << 2) + reg;
                redS1[w][row] = a;
                redS2[w][row] = q;
            }
        }
    }
    __syncthreads();

    if (tid < 64) {
        float S1 = 0.f, S2 = 0.f;
        #pragma unroll
        for (int i = 0; i < 8; ++i) { S1 += redS1[i][tid]; S2 += redS2[i][tid]; }
        const float mu = S1 * (1.0f / HID2);
        const float var = S2 * (1.0f / HID2) - mu * mu;
        muv[tid] = mu;
        rsv[tid] = rsqrtf(var + LN_EPS);
    }
    __syncthreads();

    #pragma unroll
    for (int rt = 0; rt < 4; ++rt) {
        float tpart[4] = {0.f, 0.f, 0.f, 0.f};
        float mus[4], rss[4];
        #pragma unroll
        for (int reg = 0; reg < 4; ++reg) {
            const int row = (rt << 4) + (gq << 2) + reg;
            mus[reg] = muv[row];
            rss[reg] = rsv[row];
        }
        #pragma unroll
        for (int ct = 0; ct < 4; ++ct) {
            const int c = wcol0 + (ct << 4) + lc;
            const float lg = prm[512 + c], lb = prm[1024 + c], w2 = prm[1536 + c];
            #pragma unroll
            for (int reg = 0; reg < 4; ++reg) {
                float zn = (acc[rt][ct][reg] - mus[reg]) * rss[reg] * lg + lb;
                zn = fmaxf(zn, 0.f);
                tpart[reg] = fmaf(zn, w2, tpart[reg]);
            }
        }
        #pragma unroll
        for (int reg = 0; reg < 4; ++reg) {
            float t = tpart[reg];
            t += __shfl_xor(t, 1); t += __shfl_xor(t, 2);
            t += __shfl_xor(t, 4); t += __shfl_xor(t, 8);
            if (lc == 0) redT[w][(rt << 4) + (gq << 2) + reg] = t;
        }
    }
    __syncthreads();

    if (tid < 64) {
        float t = 0.f;
        #pragma unroll
        for (int i = 0; i < 8; ++i) t += redT[i][tid];
        logits[row0 + tid] = t + b2[0];
    }
}

// ---------------------------------------------------------------------------
// K2: per-graph softmax + seed selection (first-index max of node_prob).
// ---------------------------------------------------------------------------
__global__ __launch_bounds__(256)
void softmax_seed_kernel(const float* __restrict__ logits,
                         float* __restrict__ out_prob,
                         unsigned char* __restrict__ nm)
{
    const int gid  = blockIdx.x;
    const int tid  = threadIdx.x;
    const int node = gid * NPG + tid;
    const bool act = tid < NPG;

    __shared__ float redf[4];
    __shared__ int   redi[4];

    float l = act ? logits[node] : -INFINITY;

    float m = l;
    #pragma unroll
    for (int off = 32; off >= 1; off >>= 1) m = fmaxf(m, __shfl_xor(m, off));
    if ((tid & 63) == 0) redf[tid >> 6] = m;
    __syncthreads();
    const float bm = fmaxf(fmaxf(redf[0], redf[1]), fmaxf(redf[2], redf[3]));
    __syncthreads();

    const float e = act ? expf(l - bm) : 0.0f;
    float s = e;
    #pragma unroll
    for (int off = 32; off >= 1; off >>= 1) s += __shfl_xor(s, off);
    if ((tid & 63) == 0) redf[tid >> 6] = s;
    __syncthreads();
    const float bs = redf[0] + redf[1] + redf[2] + redf[3];
    __syncthreads();

    const float p = act ? e / bs : -1.0f;
    if (act) out_prob[node] = p;

    float pm = p;
    #pragma unroll
    for (int off = 32; off >= 1; off >>= 1) pm = fmaxf(pm, __shfl_xor(pm, off));
    if ((tid & 63) == 0) redf[tid >> 6] = pm;
    __syncthreads();
    const float bpm = fmaxf(fmaxf(redf[0], redf[1]), fmaxf(redf[2], redf[3]));

    int c = (act && p >= bpm) ? node : 0x7FFFFFFF;
    #pragma unroll
    for (int off = 32; off >= 1; off >>= 1) c = min(c, __shfl_xor(c, off));
    if ((tid & 63) == 0) redi[tid >> 6] = c;
    __syncthreads();
    if (tid == 0) {
        const int seed = min(min(redi[0], redi[1]), min(redi[2], redi[3]));
        nm[seed] = 1;   // level 1
    }
}

// ---------------------------------------------------------------------------
// K3/K4: one synchronous BFS hop (expand target -> source), level-tagged.
// 4 edges/thread, unconditional int4 src+dst loads (coalesced streams).
// ---------------------------------------------------------------------------
__global__ __launch_bounds__(256)
void bfs_pass_kernel(const int* __restrict__ ei, unsigned char* __restrict__ nm,
                     const int E, const int maxlvl, const int newlvl)
{
    const int e = (blockIdx.x * blockDim.x + threadIdx.x) << 2;
    if (e >= E) return;
    const int4 s4 = *reinterpret_cast<const int4*>(ei + e);
    const int4 d4 = *reinterpret_cast<const int4*>(ei + E + e);
    #pragma unroll
    for (int j = 0; j < 4; ++j) {
        const int d = (j == 0) ? d4.x : (j == 1) ? d4.y : (j == 2) ? d4.z : d4.w;
        const int lv = nm[d];
        if (lv >= 1 && lv <= maxlvl) {
            const int s = (j == 0) ? s4.x : (j == 1) ? s4.y : (j == 2) ? s4.z : s4.w;
            if (nm[s] == 0) nm[s] = (unsigned char)newlvl;
        }
    }
}

// ---------------------------------------------------------------------------
// K5: edge outputs + node-mask scatter (float32 outputs), 4 edges/thread.
// ---------------------------------------------------------------------------
__global__ __launch_bounds__(256)
void edge_out_kernel(const int* __restrict__ ei, const float* __restrict__ logits,
                     const unsigned char* __restrict__ nm,
                     float* __restrict__ out_ew,
                     float* __restrict__ out_em,
                     unsigned char* __restrict__ nodemask, const int E)
{
    const int e = (blockIdx.x * blockDim.x + threadIdx.x) << 2;
    if (e >= E) return;
    const int4 s4 = *reinterpret_cast<const int4*>(ei + e);
    const int4 d4 = *reinterpret_cast<const int4*>(ei + E + e);
    f32x4 ew, em;
    #pragma unroll
    for (int j = 0; j < 4; ++j) {
        const int s = (j == 0) ? s4.x : (j == 1) ? s4.y : (j == 2) ? s4.z : s4.w;
        const int d = (j == 0) ? d4.x : (j == 1) ? d4.y : (j == 2) ? d4.z : d4.w;
        ew[j] = logits[s] + logits[d];
        const bool m = (nm[s] != 0) && (nm[d] != 0);
        em[j] = m ? 1.0f : 0.0f;
        if (m) { nodemask[s] = 1; nodemask[d] = 1; }
    }
    *reinterpret_cast<f32x4*>(out_ew + e) = ew;
    *reinterpret_cast<f32x4*>(out_em + e) = em;
}

// ---------------------------------------------------------------------------
// K6: node_mask -> float32 output, 4 nodes/thread.
// ---------------------------------------------------------------------------
__global__ __launch_bounds__(256)
void node_mask_kernel(const unsigned char* __restrict__ nodemask,
                      float* __restrict__ out_nm, const int N)
{
    const int i = (blockIdx.x * blockDim.x + threadIdx.x) << 2;
    if (i >= N) return;
    const uchar4 m4 = *reinterpret_cast<const uchar4*>(nodemask + i);
    f32x4 o;
    o[0] = m4.x ? 1.0f : 0.0f;
    o[1] = m4.y ? 1.0f : 0.0f;
    o[2] = m4.z ? 1.0f : 0.0f;
    o[3] = m4.w ? 1.0f : 0.0f;
    *reinterpret_cast<f32x4*>(out_nm + i) = o;
}

// ---------------------------------------------------------------------------
// K0: zero nm + nodemask scratch
// ---------------------------------------------------------------------------
__global__ __launch_bounds__(256)
void zero_ws_kernel(uint4* __restrict__ p, const int n16)
{
    const int i = blockIdx.x * blockDim.x + threadIdx.x;
    if (i < n16) p[i] = make_uint4(0u, 0u, 0u, 0u);
}

extern "C" void kernel_launch(void* const* d_in, const int* in_sizes, int n_in,
                              void* d_out, int out_size, void* d_ws, size_t ws_size,
                              hipStream_t stream)
{
    const float* h     = (const float*)d_in[0];
    const float* g     = (const float*)d_in[1];
    const int*   batch = (const int*)d_in[2];
    const int*   ei    = (const int*)d_in[3];
    const float* W1    = (const float*)d_in[4];
    const float* b1    = (const float*)d_in[5];
    const float* lng   = (const float*)d_in[6];
    const float* lnb   = (const float*)d_in[7];
    const float* W2    = (const float*)d_in[8];
    const float* b2    = (const float*)d_in[9];

    const int N = in_sizes[2];
    const int E = in_sizes[3] / 2;

    float* out        = (float*)d_out;
    float* out_prob   = out;                                  // [N]
    float* out_ew     = out + N;                              // [E]
    float* out_em     = out + (size_t)N + E;                  // [E]
    float* out_nmask  = out + (size_t)N + 2 * (size_t)E;      // [N]

    // workspace layout
    char* ws = (char*)d_ws;
    float*         logits   = (float*)ws;                               // N*4
    ushort_t*      w1h      = (ushort_t*)(ws + (size_t)N * 4);          // 512*256*2
    ushort_t*      w1l      = (ushort_t*)(ws + (size_t)N * 4 + 262144);
    unsigned char* nm       = (unsigned char*)(ws + (size_t)N * 4 + 524288);
    unsigned char* nodemask = nm + N;

    // zero nm + nodemask (2N bytes, 16B aligned)
    const int n16 = (2 * N) / 16;
    zero_ws_kernel<<<(n16 + 255) / 256, 256, 0, stream>>>((uint4*)nm, n16);

    w1_prep_kernel<<<HID2, HID, 0, stream>>>(W1, w1h, w1l);

    mlp_logits_mfma<<<N / 64, 512, 0, stream>>>(h, g, batch, w1h, w1l,
                                                b1, lng, lnb, W2, b2, logits);
    softmax_seed_kernel<<<N / NPG, 256, 0, stream>>>(logits, out_prob, nm);
    bfs_pass_kernel<<<(E / 4 + 255) / 256, 256, 0, stream>>>(ei, nm, E, 1, 2);
    bfs_pass_kernel<<<(E / 4 + 255) / 256, 256, 0, stream>>>(ei, nm, E, 2, 3);
    edge_out_kernel<<<(E / 4 + 255) / 256, 256, 0, stream>>>(ei, logits, nm,
                                                             out_ew, out_em,
                                                             nodemask, E);
    node_mask_kernel<<<(N / 4 + 255) / 256, 256, 0, stream>>>(nodemask, out_nmask, N);
}

// Round 13
// 212.924 us; speedup vs baseline: 1.3060x; 1.0934x over previous
//
#include <hip/hip_runtime.h>
#include <hip/hip_bf16.h>

#define HID 256
#define HID2 512
#define NPG 200
#define LN_EPS 1e-5f

typedef float f32x4 __attribute__((ext_vector_type(4)));
typedef float f32x2 __attribute__((ext_vector_type(2)));
typedef short s16x8 __attribute__((ext_vector_type(8)));
typedef unsigned short ushort_t;

// round-to-nearest-even float -> bf16 bit pattern
__device__ __forceinline__ ushort_t f2bf_rne(float x) {
    union { float f; unsigned int u; } c; c.f = x;
    unsigned int u = c.u;
    return (ushort_t)((u + 0x7fffu + ((u >> 16) & 1u)) >> 16);
}
__device__ __forceinline__ float bf2f(ushort_t h) {
    union { unsigned int u; float f; } c; c.u = ((unsigned int)h) << 16;
    return c.f;
}

// ---------------------------------------------------------------------------
// K_w1: W1[256][512] -> fragment-major bf16 hi/lo buffers.
// Layout: w1f[(((tile*8 + kq)*64) + lane)*8 + j], lane = gq*16+lc,
// holding W1[k][col] with col = tile*16+lc, k = kq*32+gq*8+j.
// ---------------------------------------------------------------------------
__global__ __launch_bounds__(256)
void w1_prep_kernel(const float* __restrict__ W1,
                    ushort_t* __restrict__ w1h, ushort_t* __restrict__ w1l)
{
    const int col = blockIdx.x;    // 0..511
    const int k   = threadIdx.x;   // 0..255
    const float v = W1[(size_t)k * HID2 + col];
    const ushort_t hi = f2bf_rne(v);
    const ushort_t lo = f2bf_rne(v - bf2f(hi));
    const int tile = col >> 4, lc = col & 15;
    const int kq = k >> 5, gq = (k >> 3) & 3, j = k & 7;
    const size_t idx = ((((size_t)tile << 3) + kq) * 64 + (gq << 4) + lc) * 8 + j;
    w1h[idx] = hi;
    w1l[idx] = lo;
}

// ---------------------------------------------------------------------------
// K1: fused  x = h + g[batch];  z = x@W1 + b1;  LayerNorm; ReLU; logit = z.W2+b2
// bf16x3 MFMA, fully-unrolled STATIC K-loop. BM=32 (was 64): LDS ~43KB ->
// 3 blocks/CU, acc 32 VGPR -> ~20 waves/CU (was ~12). Wave w owns cols
// w*64..+63 x rows 0..31. NT h loads protect L2-resident W1.
// NOTE (twice-measured): runtime-dependent K offsets spill to scratch
// (~150-900MB phantom traffic, r9/r11). Keep every offset static.
// ---------------------------------------------------------------------------
__global__ __launch_bounds__(512, 4)
void mlp_logits_mfma(const float* __restrict__ h, const float* __restrict__ g,
                     const int* __restrict__ batch,
                     const ushort_t* __restrict__ w1h, const ushort_t* __restrict__ w1l,
                     const float* __restrict__ b1,
                     const float* __restrict__ lng, const float* __restrict__ lnb,
                     const float* __restrict__ W2, const float* __restrict__ b2,
                     float* __restrict__ logits)
{
    __shared__ ushort_t xsh[32 * 256];   // 16 KB, swizzled
    __shared__ ushort_t xsl[32 * 256];   // 16 KB, swizzled
    __shared__ float prm[4 * 512];       // b1 | lng | lnb | W2 (8 KB)
    __shared__ float redS1[8][32];
    __shared__ float redS2[8][32];
    __shared__ float redT[8][32];
    __shared__ float muv[32], rsv[32];

    const int tid  = threadIdx.x;
    const int row0 = blockIdx.x * 32;

    // ---- params -> LDS ----
    {
        const int c = tid;               // 0..511
        prm[c]        = b1[c];
        prm[512 + c]  = lng[c];
        prm[1024 + c] = lnb[c];
        prm[1536 + c] = W2[c];
    }

    // ---- stage x = h + g[batch], split to bf16 hi/lo in swizzled LDS ----
    #pragma unroll
    for (int i = 0; i < 2; ++i) {
        const int ci = tid + (i << 9);      // 0..1023
        const int r  = ci >> 5;             // 0..31
        const int kc = (ci & 31) << 3;      // 0..248
        const int grow = row0 + r;
        const int gb   = batch[grow];
        const f32x4* hp = reinterpret_cast<const f32x4*>(h + (size_t)grow * HID + kc);
        const f32x4* gp = reinterpret_cast<const f32x4*>(g + (size_t)gb   * HID + kc);
        const f32x4 h0 = __builtin_nontemporal_load(hp);
        const f32x4 h1 = __builtin_nontemporal_load(hp + 1);
        const f32x4 g0 = gp[0], g1 = gp[1];
        float xv[8] = { h0.x + g0.x, h0.y + g0.y, h0.z + g0.z, h0.w + g0.w,
                        h1.x + g1.x, h1.y + g1.y, h1.z + g1.z, h1.w + g1.w };
        ushort_t hh[8], ll[8];
        #pragma unroll
        for (int j = 0; j < 8; ++j) {
            const ushort_t hi = f2bf_rne(xv[j]);
            hh[j] = hi;
            ll[j] = f2bf_rne(xv[j] - bf2f(hi));
        }
        int byte_off = r * 512 + (kc << 1);
        byte_off ^= (r & 7) << 4;
        *reinterpret_cast<s16x8*>(reinterpret_cast<char*>(xsh) + byte_off) =
            *reinterpret_cast<const s16x8*>(hh);
        *reinterpret_cast<s16x8*>(reinterpret_cast<char*>(xsl) + byte_off) =
            *reinterpret_cast<const s16x8*>(ll);
    }
    __syncthreads();

    const int w  = tid >> 6;       // wave 0..7 -> cols w*64..+63
    const int l  = tid & 63;
    const int lc = l & 15;         // A-row / B-col / C-col index within tile
    const int gq = l >> 4;         // k-chunk group 0..3 (and C row group)
    const int wcol0 = w << 6;

    f32x4 acc[2][4];               // [rt][ct]
    #pragma unroll
    for (int rt = 0; rt < 2; ++rt)
        #pragma unroll
        for (int ct = 0; ct < 4; ++ct) acc[rt][ct] = (f32x4){0.f, 0.f, 0.f, 0.f};

    // fragment-major B base for this wave+lane: tiles w*4..w*4+3
    const ushort_t* bfh = w1h + (((size_t)w << 2) << 3) * 512 + (size_t)l * 8;
    const ushort_t* bfl = w1l + (((size_t)w << 2) << 3) * 512 + (size_t)l * 8;

    #pragma unroll
    for (int kq = 0; kq < 8; ++kq) {
        // B fragments: coalesced 1KB wave loads, (ct*8+kq)*512 elements apart
        s16x8 bh[4], bl[4];
        #pragma unroll
        for (int ct = 0; ct < 4; ++ct) {
            const size_t foff = (size_t)((ct << 3) + kq) * 512;
            bh[ct] = *reinterpret_cast<const s16x8*>(bfh + foff);
            bl[ct] = *reinterpret_cast<const s16x8*>(bfl + foff);
        }
        // A fragments: row = rt*16 + lc, k = kq*32 + gq*8
        s16x8 ah[2], al[2];
        #pragma unroll
        for (int rt = 0; rt < 2; ++rt) {
            const int arow = (rt << 4) | lc;
            int abyte = arow * 512 + (((kq << 5) + (gq << 3)) << 1);
            abyte ^= (arow & 7) << 4;
            ah[rt] = *reinterpret_cast<const s16x8*>(
                         reinterpret_cast<const char*>(xsh) + abyte);
            al[rt] = *reinterpret_cast<const s16x8*>(
                         reinterpret_cast<const char*>(xsl) + abyte);
        }
        // term-outer MFMA order: 8 independent accs between same-acc reuse
        #pragma unroll
        for (int ct = 0; ct < 4; ++ct)
            #pragma unroll
            for (int rt = 0; rt < 2; ++rt)
                acc[rt][ct] = __builtin_amdgcn_mfma_f32_16x16x32_bf16(ah[rt], bh[ct], acc[rt][ct], 0, 0, 0);
        #pragma unroll
        for (int ct = 0; ct < 4; ++ct)
            #pragma unroll
            for (int rt = 0; rt < 2; ++rt)
                acc[rt][ct] = __builtin_amdgcn_mfma_f32_16x16x32_bf16(al[rt], bh[ct], acc[rt][ct], 0, 0, 0);
        #pragma unroll
        for (int ct = 0; ct < 4; ++ct)
            #pragma unroll
            for (int rt = 0; rt < 2; ++rt)
                acc[rt][ct] = __builtin_amdgcn_mfma_f32_16x16x32_bf16(ah[rt], bl[ct], acc[rt][ct], 0, 0, 0);
    }

    // ---- epilogue ----
    // C-layout per (rt,ct) tile: lane holds col wcol0+ct*16+lc, row rt*16+gq*4+reg.
    #pragma unroll
    for (int rt = 0; rt < 2; ++rt) {
        float s1[4] = {0.f, 0.f, 0.f, 0.f};
        float s2[4] = {0.f, 0.f, 0.f, 0.f};
        #pragma unroll
        for (int ct = 0; ct < 4; ++ct) {
            const float bb = prm[wcol0 + (ct << 4) + lc];
            #pragma unroll
            for (int reg = 0; reg < 4; ++reg) {
                const float v = acc[rt][ct][reg] + bb;
                acc[rt][ct][reg] = v;
                s1[reg] += v;
                s2[reg] = fmaf(v, v, s2[reg]);
            }
        }
        #pragma unroll
        for (int reg = 0; reg < 4; ++reg) {
            float a = s1[reg], q = s2[reg];
            a += __shfl_xor(a, 1); q += __shfl_xor(q, 1);
            a += __shfl_xor(a, 2); q += __shfl_xor(q, 2);
            a += __shfl_xor(a, 4); q += __shfl_xor(q, 4);
            a += __shfl_xor(a, 8); q += __shfl_xor(q, 8);
            if (lc == 0) {
                const int row = (rt << 4) + (gq << 2) + reg;
                redS1[w][row] = a;
                redS2[w][row] = q;
            }
        }
    }
    __syncthreads();

    if (tid < 32) {
        float S1 = 0.f, S2 = 0.f;
        #pragma unroll
        for (int i = 0; i < 8; ++i) { S1 += redS1[i][tid]; S2 += redS2[i][tid]; }
        const float mu = S1 * (1.0f / HID2);
        const float var = S2 * (1.0f / HID2) - mu * mu;
        muv[tid] = mu;
        rsv[tid] = rsqrtf(var + LN_EPS);
    }
    __syncthreads();

    #pragma unroll
    for (int rt = 0; rt < 2; ++rt) {
        float tpart[4] = {0.f, 0.f, 0.f, 0.f};
        float mus[4], rss[4];
        #pragma unroll
        for (int reg = 0; reg < 4; ++reg) {
            const int row = (rt << 4) + (gq << 2) + reg;
            mus[reg] = muv[row];
            rss[reg] = rsv[row];
        }
        #pragma unroll
        for (int ct = 0; ct < 4; ++ct) {
            const int c = wcol0 + (ct << 4) + lc;
            const float lg = prm[512 + c], lb = prm[1024 + c], w2 = prm[1536 + c];
            #pragma unroll
            for (int reg = 0; reg < 4; ++reg) {
                float zn = (acc[rt][ct][reg] - mus[reg]) * rss[reg] * lg + lb;
                zn = fmaxf(zn, 0.f);
                tpart[reg] = fmaf(zn, w2, tpart[reg]);
            }
        }
        #pragma unroll
        for (int reg = 0; reg < 4; ++reg) {
            float t = tpart[reg];
            t += __shfl_xor(t, 1); t += __shfl_xor(t, 2);
            t += __shfl_xor(t, 4); t += __shfl_xor(t, 8);
            if (lc == 0) redT[w][(rt << 4) + (gq << 2) + reg] = t;
        }
    }
    __syncthreads();

    if (tid < 32) {
        float t = 0.f;
        #pragma unroll
        for (int i = 0; i < 8; ++i) t += redT[i][tid];
        logits[row0 + tid] = t + b2[0];
    }
}

// ---------------------------------------------------------------------------
// K2: per-graph softmax + seed selection (first-index max of node_prob).
// ---------------------------------------------------------------------------
__global__ __launch_bounds__(256)
void softmax_seed_kernel(const float* __restrict__ logits,
                         float* __restrict__ out_prob,
                         unsigned char* __restrict__ nm)
{
    const int gid  = blockIdx.x;
    const int tid  = threadIdx.x;
    const int node = gid * NPG + tid;
    const bool act = tid < NPG;

    __shared__ float redf[4];
    __shared__ int   redi[4];

    float l = act ? logits[node] : -INFINITY;

    float m = l;
    #pragma unroll
    for (int off = 32; off >= 1; off >>= 1) m = fmaxf(m, __shfl_xor(m, off));
    if ((tid & 63) == 0) redf[tid >> 6] = m;
    __syncthreads();
    const float bm = fmaxf(fmaxf(redf[0], redf[1]), fmaxf(redf[2], redf[3]));
    __syncthreads();

    const float e = act ? expf(l - bm) : 0.0f;
    float s = e;
    #pragma unroll
    for (int off = 32; off >= 1; off >>= 1) s += __shfl_xor(s, off);
    if ((tid & 63) == 0) redf[tid >> 6] = s;
    __syncthreads();
    const float bs = redf[0] + redf[1] + redf[2] + redf[3];
    __syncthreads();

    const float p = act ? e / bs : -1.0f;
    if (act) out_prob[node] = p;

    float pm = p;
    #pragma unroll
    for (int off = 32; off >= 1; off >>= 1) pm = fmaxf(pm, __shfl_xor(pm, off));
    if ((tid & 63) == 0) redf[tid >> 6] = pm;
    __syncthreads();
    const float bpm = fmaxf(fmaxf(redf[0], redf[1]), fmaxf(redf[2], redf[3]));

    int c = (act && p >= bpm) ? node : 0x7FFFFFFF;
    #pragma unroll
    for (int off = 32; off >= 1; off >>= 1) c = min(c, __shfl_xor(c, off));
    if ((tid & 63) == 0) redi[tid >> 6] = c;
    __syncthreads();
    if (tid == 0) {
        const int seed = min(min(redi[0], redi[1]), min(redi[2], redi[3]));
        nm[seed] = 1;   // level 1
    }
}

// ---------------------------------------------------------------------------
// K3/K4: one synchronous BFS hop (expand target -> source), level-tagged.
// 4 edges/thread, unconditional int4 src+dst loads (coalesced streams).
// ---------------------------------------------------------------------------
__global__ __launch_bounds__(256)
void bfs_pass_kernel(const int* __restrict__ ei, unsigned char* __restrict__ nm,
                     const int E, const int maxlvl, const int newlvl)
{
    const int e = (blockIdx.x * blockDim.x + threadIdx.x) << 2;
    if (e >= E) return;
    const int4 s4 = *reinterpret_cast<const int4*>(ei + e);
    const int4 d4 = *reinterpret_cast<const int4*>(ei + E + e);
    #pragma unroll
    for (int j = 0; j < 4; ++j) {
        const int d = (j == 0) ? d4.x : (j == 1) ? d4.y : (j == 2) ? d4.z : d4.w;
        const int lv = nm[d];
        if (lv >= 1 && lv <= maxlvl) {
            const int s = (j == 0) ? s4.x : (j == 1) ? s4.y : (j == 2) ? s4.z : s4.w;
            if (nm[s] == 0) nm[s] = (unsigned char)newlvl;
        }
    }
}

// ---------------------------------------------------------------------------
// K4b: pack {logit, nm-flag} into 8B entries (halves edge_out's gather count).
// ---------------------------------------------------------------------------
__global__ __launch_bounds__(256)
void pack_kernel(const float* __restrict__ logits,
                 const unsigned char* __restrict__ nm,
                 f32x2* __restrict__ pk, const int N)
{
    const int i = blockIdx.x * blockDim.x + threadIdx.x;
    if (i < N) {
        f32x2 v;
        v.x = logits[i];
        v.y = nm[i] ? 1.0f : 0.0f;
        pk[i] = v;
    }
}

// ---------------------------------------------------------------------------
// K5: edge outputs + node-mask scatter, 4 edges/thread, packed 8B gathers.
// ---------------------------------------------------------------------------
__global__ __launch_bounds__(256)
void edge_out_kernel(const int* __restrict__ ei, const f32x2* __restrict__ pk,
                     float* __restrict__ out_ew,
                     float* __restrict__ out_em,
                     unsigned char* __restrict__ nodemask, const int E)
{
    const int e = (blockIdx.x * blockDim.x + threadIdx.x) << 2;
    if (e >= E) return;
    const int4 s4 = *reinterpret_cast<const int4*>(ei + e);
    const int4 d4 = *reinterpret_cast<const int4*>(ei + E + e);
    f32x4 ew, em;
    #pragma unroll
    for (int j = 0; j < 4; ++j) {
        const int s = (j == 0) ? s4.x : (j == 1) ? s4.y : (j == 2) ? s4.z : s4.w;
        const int d = (j == 0) ? d4.x : (j == 1) ? d4.y : (j == 2) ? d4.z : d4.w;
        const f32x2 ps = pk[s];
        const f32x2 pd = pk[d];
        ew[j] = ps.x + pd.x;
        const bool m = (ps.y != 0.0f) && (pd.y != 0.0f);
        em[j] = m ? 1.0f : 0.0f;
        if (m) { nodemask[s] = 1; nodemask[d] = 1; }
    }
    *reinterpret_cast<f32x4*>(out_ew + e) = ew;
    *reinterpret_cast<f32x4*>(out_em + e) = em;
}

// ---------------------------------------------------------------------------
// K6: node_mask -> float32 output, 4 nodes/thread.
// ---------------------------------------------------------------------------
__global__ __launch_bounds__(256)
void node_mask_kernel(const unsigned char* __restrict__ nodemask,
                      float* __restrict__ out_nm, const int N)
{
    const int i = (blockIdx.x * blockDim.x + threadIdx.x) << 2;
    if (i >= N) return;
    const uchar4 m4 = *reinterpret_cast<const uchar4*>(nodemask + i);
    f32x4 o;
    o[0] = m4.x ? 1.0f : 0.0f;
    o[1] = m4.y ? 1.0f : 0.0f;
    o[2] = m4.z ? 1.0f : 0.0f;
    o[3] = m4.w ? 1.0f : 0.0f;
    *reinterpret_cast<f32x4*>(out_nm + i) = o;
}

// ---------------------------------------------------------------------------
// K0: zero nm + nodemask scratch
// ---------------------------------------------------------------------------
__global__ __launch_bounds__(256)
void zero_ws_kernel(uint4* __restrict__ p, const int n16)
{
    const int i = blockIdx.x * blockDim.x + threadIdx.x;
    if (i < n16) p[i] = make_uint4(0u, 0u, 0u, 0u);
}

extern "C" void kernel_launch(void* const* d_in, const int* in_sizes, int n_in,
                              void* d_out, int out_size, void* d_ws, size_t ws_size,
                              hipStream_t stream)
{
    const float* h     = (const float*)d_in[0];
    const float* g     = (const float*)d_in[1];
    const int*   batch = (const int*)d_in[2];
    const int*   ei    = (const int*)d_in[3];
    const float* W1    = (const float*)d_in[4];
    const float* b1    = (const float*)d_in[5];
    const float* lng   = (const float*)d_in[6];
    const float* lnb   = (const float*)d_in[7];
    const float* W2    = (const float*)d_in[8];
    const float* b2    = (const float*)d_in[9];

    const int N = in_sizes[2];
    const int E = in_sizes[3] / 2;

    float* out        = (float*)d_out;
    float* out_prob   = out;                                  // [N]
    float* out_ew     = out + N;                              // [E]
    float* out_em     = out + (size_t)N + E;                  // [E]
    float* out_nmask  = out + (size_t)N + 2 * (size_t)E;      // [N]

    // workspace layout
    char* ws = (char*)d_ws;
    float*         logits   = (float*)ws;                                // N*4
    ushort_t*      w1h      = (ushort_t*)(ws + (size_t)N * 4);           // 256 KB
    ushort_t*      w1l      = (ushort_t*)(ws + (size_t)N * 4 + 262144);  // 256 KB
    unsigned char* nm       = (unsigned char*)(ws + (size_t)N * 4 + 524288);
    unsigned char* nodemask = nm + N;
    f32x2*         pk       = (f32x2*)(ws + (size_t)N * 4 + 524288 + 2 * (size_t)N);

    // zero nm + nodemask (2N bytes, 16B aligned)
    const int n16 = (2 * N) / 16;
    zero_ws_kernel<<<(n16 + 255) / 256, 256, 0, stream>>>((uint4*)nm, n16);

    w1_prep_kernel<<<HID2, HID, 0, stream>>>(W1, w1h, w1l);

    mlp_logits_mfma<<<N / 32, 512, 0, stream>>>(h, g, batch, w1h, w1l,
                                                b1, lng, lnb, W2, b2, logits);
    softmax_seed_kernel<<<N / NPG, 256, 0, stream>>>(logits, out_prob, nm);
    bfs_pass_kernel<<<(E / 4 + 255) / 256, 256, 0, stream>>>(ei, nm, E, 1, 2);
    bfs_pass_kernel<<<(E / 4 + 255) / 256, 256, 0, stream>>>(ei, nm, E, 2, 3);
    pack_kernel<<<(N + 255) / 256, 256, 0, stream>>>(logits, nm, pk, N);
    edge_out_kernel<<<(E / 4 + 255) / 256, 256, 0, stream>>>(ei, pk,
                                                             out_ew, out_em,
                                                             nodemask, E);
    node_mask_kernel<<<(N / 4 + 255) / 256, 256, 0, stream>>>(nodemask, out_nmask, N);
}

// Round 14
// 212.811 us; speedup vs baseline: 1.3067x; 1.0005x over previous
//
#include <hip/hip_runtime.h>
#include <hip/hip_bf16.h>

#define HID 256
#define HID2 512
#define NPG 200
#define LN_EPS 1e-5f

typedef float f32x4 __attribute__((ext_vector_type(4)));
typedef float f32x2 __attribute__((ext_vector_type(2)));
typedef short s16x8 __attribute__((ext_vector_type(8)));
typedef unsigned short ushort_t;

// round-to-nearest-even float -> bf16 bit pattern
__device__ __forceinline__ ushort_t f2bf_rne(float x) {
    union { float f; unsigned int u; } c; c.f = x;
    unsigned int u = c.u;
    return (ushort_t)((u + 0x7fffu + ((u >> 16) & 1u)) >> 16);
}
__device__ __forceinline__ float bf2f(ushort_t h) {
    union { unsigned int u; float f; } c; c.u = ((unsigned int)h) << 16;
    return c.f;
}

// ---------------------------------------------------------------------------
// K_w1: W1[256][512] -> fragment-major bf16 hi/lo buffers.
// ---------------------------------------------------------------------------
__global__ __launch_bounds__(256)
void w1_prep_kernel(const float* __restrict__ W1,
                    ushort_t* __restrict__ w1h, ushort_t* __restrict__ w1l)
{
    const int col = blockIdx.x;    // 0..511
    const int k   = threadIdx.x;   // 0..255
    const float v = W1[(size_t)k * HID2 + col];
    const ushort_t hi = f2bf_rne(v);
    const ushort_t lo = f2bf_rne(v - bf2f(hi));
    const int tile = col >> 4, lc = col & 15;
    const int kq = k >> 5, gq = (k >> 3) & 3, j = k & 7;
    const size_t idx = ((((size_t)tile << 3) + kq) * 64 + (gq << 4) + lc) * 8 + j;
    w1h[idx] = hi;
    w1l[idx] = lo;
}

// ---------------------------------------------------------------------------
// K1: fused  x = h + g[batch];  z = x@W1 + b1;  LayerNorm; ReLU; logit = z.W2+b2
// bf16x3 MFMA, fully-unrolled STATIC K-loop, BM=32 (r13 known-good, 132 us).
// Plateau notes (measured): time invariant across BM{32,64}, occupancy capped
// by unified regfile (52 VGPR + 32 AGPR -> 4 waves/SIMD, 2 blocks/CU);
// runtime-dependent K offsets spill (r9/r11). Do not restructure casually.
// ---------------------------------------------------------------------------
__global__ __launch_bounds__(512, 4)
void mlp_logits_mfma(const float* __restrict__ h, const float* __restrict__ g,
                     const int* __restrict__ batch,
                     const ushort_t* __restrict__ w1h, const ushort_t* __restrict__ w1l,
                     const float* __restrict__ b1,
                     const float* __restrict__ lng, const float* __restrict__ lnb,
                     const float* __restrict__ W2, const float* __restrict__ b2,
                     float* __restrict__ logits)
{
    __shared__ ushort_t xsh[32 * 256];   // 16 KB, swizzled
    __shared__ ushort_t xsl[32 * 256];   // 16 KB, swizzled
    __shared__ float prm[4 * 512];       // b1 | lng | lnb | W2 (8 KB)
    __shared__ float redS1[8][32];
    __shared__ float redS2[8][32];
    __shared__ float redT[8][32];
    __shared__ float muv[32], rsv[32];

    const int tid  = threadIdx.x;
    const int row0 = blockIdx.x * 32;

    // ---- params -> LDS ----
    {
        const int c = tid;               // 0..511
        prm[c]        = b1[c];
        prm[512 + c]  = lng[c];
        prm[1024 + c] = lnb[c];
        prm[1536 + c] = W2[c];
    }

    // ---- stage x = h + g[batch], split to bf16 hi/lo in swizzled LDS ----
    #pragma unroll
    for (int i = 0; i < 2; ++i) {
        const int ci = tid + (i << 9);      // 0..1023
        const int r  = ci >> 5;             // 0..31
        const int kc = (ci & 31) << 3;      // 0..248
        const int grow = row0 + r;
        const int gb   = batch[grow];
        const f32x4* hp = reinterpret_cast<const f32x4*>(h + (size_t)grow * HID + kc);
        const f32x4* gp = reinterpret_cast<const f32x4*>(g + (size_t)gb   * HID + kc);
        const f32x4 h0 = __builtin_nontemporal_load(hp);
        const f32x4 h1 = __builtin_nontemporal_load(hp + 1);
        const f32x4 g0 = gp[0], g1 = gp[1];
        float xv[8] = { h0.x + g0.x, h0.y + g0.y, h0.z + g0.z, h0.w + g0.w,
                        h1.x + g1.x, h1.y + g1.y, h1.z + g1.z, h1.w + g1.w };
        ushort_t hh[8], ll[8];
        #pragma unroll
        for (int j = 0; j < 8; ++j) {
            const ushort_t hi = f2bf_rne(xv[j]);
            hh[j] = hi;
            ll[j] = f2bf_rne(xv[j] - bf2f(hi));
        }
        int byte_off = r * 512 + (kc << 1);
        byte_off ^= (r & 7) << 4;
        *reinterpret_cast<s16x8*>(reinterpret_cast<char*>(xsh) + byte_off) =
            *reinterpret_cast<const s16x8*>(hh);
        *reinterpret_cast<s16x8*>(reinterpret_cast<char*>(xsl) + byte_off) =
            *reinterpret_cast<const s16x8*>(ll);
    }
    __syncthreads();

    const int w  = tid >> 6;       // wave 0..7 -> cols w*64..+63
    const int l  = tid & 63;
    const int lc = l & 15;         // A-row / B-col / C-col index within tile
    const int gq = l >> 4;         // k-chunk group 0..3 (and C row group)
    const int wcol0 = w << 6;

    f32x4 acc[2][4];               // [rt][ct]
    #pragma unroll
    for (int rt = 0; rt < 2; ++rt)
        #pragma unroll
        for (int ct = 0; ct < 4; ++ct) acc[rt][ct] = (f32x4){0.f, 0.f, 0.f, 0.f};

    // fragment-major B base for this wave+lane: tiles w*4..w*4+3
    const ushort_t* bfh = w1h + (((size_t)w << 2) << 3) * 512 + (size_t)l * 8;
    const ushort_t* bfl = w1l + (((size_t)w << 2) << 3) * 512 + (size_t)l * 8;

    #pragma unroll
    for (int kq = 0; kq < 8; ++kq) {
        s16x8 bh[4], bl[4];
        #pragma unroll
        for (int ct = 0; ct < 4; ++ct) {
            const size_t foff = (size_t)((ct << 3) + kq) * 512;
            bh[ct] = *reinterpret_cast<const s16x8*>(bfh + foff);
            bl[ct] = *reinterpret_cast<const s16x8*>(bfl + foff);
        }
        s16x8 ah[2], al[2];
        #pragma unroll
        for (int rt = 0; rt < 2; ++rt) {
            const int arow = (rt << 4) | lc;
            int abyte = arow * 512 + (((kq << 5) + (gq << 3)) << 1);
            abyte ^= (arow & 7) << 4;
            ah[rt] = *reinterpret_cast<const s16x8*>(
                         reinterpret_cast<const char*>(xsh) + abyte);
            al[rt] = *reinterpret_cast<const s16x8*>(
                         reinterpret_cast<const char*>(xsl) + abyte);
        }
        #pragma unroll
        for (int ct = 0; ct < 4; ++ct)
            #pragma unroll
            for (int rt = 0; rt < 2; ++rt)
                acc[rt][ct] = __builtin_amdgcn_mfma_f32_16x16x32_bf16(ah[rt], bh[ct], acc[rt][ct], 0, 0, 0);
        #pragma unroll
        for (int ct = 0; ct < 4; ++ct)
            #pragma unroll
            for (int rt = 0; rt < 2; ++rt)
                acc[rt][ct] = __builtin_amdgcn_mfma_f32_16x16x32_bf16(al[rt], bh[ct], acc[rt][ct], 0, 0, 0);
        #pragma unroll
        for (int ct = 0; ct < 4; ++ct)
            #pragma unroll
            for (int rt = 0; rt < 2; ++rt)
                acc[rt][ct] = __builtin_amdgcn_mfma_f32_16x16x32_bf16(ah[rt], bl[ct], acc[rt][ct], 0, 0, 0);
    }

    // ---- epilogue ----
    #pragma unroll
    for (int rt = 0; rt < 2; ++rt) {
        float s1[4] = {0.f, 0.f, 0.f, 0.f};
        float s2[4] = {0.f, 0.f, 0.f, 0.f};
        #pragma unroll
        for (int ct = 0; ct < 4; ++ct) {
            const float bb = prm[wcol0 + (ct << 4) + lc];
            #pragma unroll
            for (int reg = 0; reg < 4; ++reg) {
                const float v = acc[rt][ct][reg] + bb;
                acc[rt][ct][reg] = v;
                s1[reg] += v;
                s2[reg] = fmaf(v, v, s2[reg]);
            }
        }
        #pragma unroll
        for (int reg = 0; reg < 4; ++reg) {
            float a = s1[reg], q = s2[reg];
            a += __shfl_xor(a, 1); q += __shfl_xor(q, 1);
            a += __shfl_xor(a, 2); q += __shfl_xor(q, 2);
            a += __shfl_xor(a, 4); q += __shfl_xor(q, 4);
            a += __shfl_xor(a, 8); q += __shfl_xor(q, 8);
            if (lc == 0) {
                const int row = (rt << 4) + (gq << 2) + reg;
                redS1[w][row] = a;
                redS2[w][row] = q;
            }
        }
    }
    __syncthreads();

    if (tid < 32) {
        float S1 = 0.f, S2 = 0.f;
        #pragma unroll
        for (int i = 0; i < 8; ++i) { S1 += redS1[i][tid]; S2 += redS2[i][tid]; }
        const float mu = S1 * (1.0f / HID2);
        const float var = S2 * (1.0f / HID2) - mu * mu;
        muv[tid] = mu;
        rsv[tid] = rsqrtf(var + LN_EPS);
    }
    __syncthreads();

    #pragma unroll
    for (int rt = 0; rt < 2; ++rt) {
        float tpart[4] = {0.f, 0.f, 0.f, 0.f};
        float mus[4], rss[4];
        #pragma unroll
        for (int reg = 0; reg < 4; ++reg) {
            const int row = (rt << 4) + (gq << 2) + reg;
            mus[reg] = muv[row];
            rss[reg] = rsv[row];
        }
        #pragma unroll
        for (int ct = 0; ct < 4; ++ct) {
            const int c = wcol0 + (ct << 4) + lc;
            const float lg = prm[512 + c], lb = prm[1024 + c], w2 = prm[1536 + c];
            #pragma unroll
            for (int reg = 0; reg < 4; ++reg) {
                float zn = (acc[rt][ct][reg] - mus[reg]) * rss[reg] * lg + lb;
                zn = fmaxf(zn, 0.f);
                tpart[reg] = fmaf(zn, w2, tpart[reg]);
            }
        }
        #pragma unroll
        for (int reg = 0; reg < 4; ++reg) {
            float t = tpart[reg];
            t += __shfl_xor(t, 1); t += __shfl_xor(t, 2);
            t += __shfl_xor(t, 4); t += __shfl_xor(t, 8);
            if (lc == 0) redT[w][(rt << 4) + (gq << 2) + reg] = t;
        }
    }
    __syncthreads();

    if (tid < 32) {
        float t = 0.f;
        #pragma unroll
        for (int i = 0; i < 8; ++i) t += redT[i][tid];
        logits[row0 + tid] = t + b2[0];
    }
}

// ---------------------------------------------------------------------------
// K2: per-graph softmax + seed selection; also zeroes this graph's nm and
// nodemask slices (200 B each, 50 uint stores) — replaces zero_ws kernel.
// ---------------------------------------------------------------------------
__global__ __launch_bounds__(256)
void softmax_seed_kernel(const float* __restrict__ logits,
                         float* __restrict__ out_prob,
                         unsigned char* __restrict__ nm,
                         unsigned char* __restrict__ nodemask)
{
    const int gid  = blockIdx.x;
    const int tid  = threadIdx.x;
    const int node = gid * NPG + tid;
    const bool act = tid < NPG;

    // zero nm + nodemask for this graph (NPG=200 bytes, 4B-aligned since 200%4==0)
    if (tid < NPG / 4) {
        reinterpret_cast<unsigned int*>(nm + gid * NPG)[tid] = 0u;
        reinterpret_cast<unsigned int*>(nodemask + gid * NPG)[tid] = 0u;
    }

    __shared__ float redf[4];
    __shared__ int   redi[4];

    float l = act ? logits[node] : -INFINITY;

    float m = l;
    #pragma unroll
    for (int off = 32; off >= 1; off >>= 1) m = fmaxf(m, __shfl_xor(m, off));
    if ((tid & 63) == 0) redf[tid >> 6] = m;
    __syncthreads();
    const float bm = fmaxf(fmaxf(redf[0], redf[1]), fmaxf(redf[2], redf[3]));
    __syncthreads();

    const float e = act ? expf(l - bm) : 0.0f;
    float s = e;
    #pragma unroll
    for (int off = 32; off >= 1; off >>= 1) s += __shfl_xor(s, off);
    if ((tid & 63) == 0) redf[tid >> 6] = s;
    __syncthreads();
    const float bs = redf[0] + redf[1] + redf[2] + redf[3];
    __syncthreads();

    const float p = act ? e / bs : -1.0f;
    if (act) out_prob[node] = p;

    float pm = p;
    #pragma unroll
    for (int off = 32; off >= 1; off >>= 1) pm = fmaxf(pm, __shfl_xor(pm, off));
    if ((tid & 63) == 0) redf[tid >> 6] = pm;
    __syncthreads();
    const float bpm = fmaxf(fmaxf(redf[0], redf[1]), fmaxf(redf[2], redf[3]));

    int c = (act && p >= bpm) ? node : 0x7FFFFFFF;
    #pragma unroll
    for (int off = 32; off >= 1; off >>= 1) c = min(c, __shfl_xor(c, off));
    if ((tid & 63) == 0) redi[tid >> 6] = c;
    __syncthreads();
    if (tid == 0) {
        const int seed = min(min(redi[0], redi[1]), min(redi[2], redi[3]));
        nm[seed] = 1;   // level 1
    }
}

// ---------------------------------------------------------------------------
// K3/K4: one synchronous BFS hop (expand target -> source), level-tagged.
// Vectorized d-stream (int4), CONDITIONAL scalar s loads (~0.2%/16% taken).
// ---------------------------------------------------------------------------
__global__ __launch_bounds__(256)
void bfs_pass_kernel(const int* __restrict__ ei, unsigned char* __restrict__ nm,
                     const int E, const int maxlvl, const int newlvl)
{
    const int e = (blockIdx.x * blockDim.x + threadIdx.x) << 2;
    if (e >= E) return;
    const int4 d4 = *reinterpret_cast<const int4*>(ei + E + e);
    #pragma unroll
    for (int j = 0; j < 4; ++j) {
        const int d = (j == 0) ? d4.x : (j == 1) ? d4.y : (j == 2) ? d4.z : d4.w;
        const int lv = nm[d];
        if (lv >= 1 && lv <= maxlvl) {
            const int s = ei[e + j];
            if (nm[s] == 0) nm[s] = (unsigned char)newlvl;
        }
    }
}

// ---------------------------------------------------------------------------
// K4b: pack {logit, nm-flag} into 8B entries (halves edge_out's gather count).
// ---------------------------------------------------------------------------
__global__ __launch_bounds__(256)
void pack_kernel(const float* __restrict__ logits,
                 const unsigned char* __restrict__ nm,
                 f32x2* __restrict__ pk, const int N)
{
    const int i = blockIdx.x * blockDim.x + threadIdx.x;
    if (i < N) {
        f32x2 v;
        v.x = logits[i];
        v.y = nm[i] ? 1.0f : 0.0f;
        pk[i] = v;
    }
}

// ---------------------------------------------------------------------------
// K5: edge outputs + node-mask scatter, 4 edges/thread, packed 8B gathers.
// ---------------------------------------------------------------------------
__global__ __launch_bounds__(256)
void edge_out_kernel(const int* __restrict__ ei, const f32x2* __restrict__ pk,
                     float* __restrict__ out_ew,
                     float* __restrict__ out_em,
                     unsigned char* __restrict__ nodemask, const int E)
{
    const int e = (blockIdx.x * blockDim.x + threadIdx.x) << 2;
    if (e >= E) return;
    const int4 s4 = *reinterpret_cast<const int4*>(ei + e);
    const int4 d4 = *reinterpret_cast<const int4*>(ei + E + e);
    f32x4 ew, em;
    #pragma unroll
    for (int j = 0; j < 4; ++j) {
        const int s = (j == 0) ? s4.x : (j == 1) ? s4.y : (j == 2) ? s4.z : s4.w;
        const int d = (j == 0) ? d4.x : (j == 1) ? d4.y : (j == 2) ? d4.z : d4.w;
        const f32x2 ps = pk[s];
        const f32x2 pd = pk[d];
        ew[j] = ps.x + pd.x;
        const bool m = (ps.y != 0.0f) && (pd.y != 0.0f);
        em[j] = m ? 1.0f : 0.0f;
        if (m) { nodemask[s] = 1; nodemask[d] = 1; }
    }
    *reinterpret_cast<f32x4*>(out_ew + e) = ew;
    *reinterpret_cast<f32x4*>(out_em + e) = em;
}

// ---------------------------------------------------------------------------
// K6: node_mask -> float32 output, 4 nodes/thread.
// ---------------------------------------------------------------------------
__global__ __launch_bounds__(256)
void node_mask_kernel(const unsigned char* __restrict__ nodemask,
                      float* __restrict__ out_nm, const int N)
{
    const int i = (blockIdx.x * blockDim.x + threadIdx.x) << 2;
    if (i >= N) return;
    const uchar4 m4 = *reinterpret_cast<const uchar4*>(nodemask + i);
    f32x4 o;
    o[0] = m4.x ? 1.0f : 0.0f;
    o[1] = m4.y ? 1.0f : 0.0f;
    o[2] = m4.z ? 1.0f : 0.0f;
    o[3] = m4.w ? 1.0f : 0.0f;
    *reinterpret_cast<f32x4*>(out_nm + i) = o;
}

extern "C" void kernel_launch(void* const* d_in, const int* in_sizes, int n_in,
                              void* d_out, int out_size, void* d_ws, size_t ws_size,
                              hipStream_t stream)
{
    const float* h     = (const float*)d_in[0];
    const float* g     = (const float*)d_in[1];
    const int*   batch = (const int*)d_in[2];
    const int*   ei    = (const int*)d_in[3];
    const float* W1    = (const float*)d_in[4];
    const float* b1    = (const float*)d_in[5];
    const float* lng   = (const float*)d_in[6];
    const float* lnb   = (const float*)d_in[7];
    const float* W2    = (const float*)d_in[8];
    const float* b2    = (const float*)d_in[9];

    const int N = in_sizes[2];
    const int E = in_sizes[3] / 2;

    float* out        = (float*)d_out;
    float* out_prob   = out;                                  // [N]
    float* out_ew     = out + N;                              // [E]
    float* out_em     = out + (size_t)N + E;                  // [E]
    float* out_nmask  = out + (size_t)N + 2 * (size_t)E;      // [N]

    // workspace layout
    char* ws = (char*)d_ws;
    float*         logits   = (float*)ws;                                // N*4
    ushort_t*      w1h      = (ushort_t*)(ws + (size_t)N * 4);           // 256 KB
    ushort_t*      w1l      = (ushort_t*)(ws + (size_t)N * 4 + 262144);  // 256 KB
    unsigned char* nm       = (unsigned char*)(ws + (size_t)N * 4 + 524288);
    unsigned char* nodemask = nm + N;
    f32x2*         pk       = (f32x2*)(ws + (size_t)N * 4 + 524288 + 2 * (size_t)N);

    w1_prep_kernel<<<HID2, HID, 0, stream>>>(W1, w1h, w1l);

    mlp_logits_mfma<<<N / 32, 512, 0, stream>>>(h, g, batch, w1h, w1l,
                                                b1, lng, lnb, W2, b2, logits);
    softmax_seed_kernel<<<N / NPG, 256, 0, stream>>>(logits, out_prob, nm, nodemask);
    bfs_pass_kernel<<<(E / 4 + 255) / 256, 256, 0, stream>>>(ei, nm, E, 1, 2);
    bfs_pass_kernel<<<(E / 4 + 255) / 256, 256, 0, stream>>>(ei, nm, E, 2, 3);
    pack_kernel<<<(N + 255) / 256, 256, 0, stream>>>(logits, nm, pk, N);
    edge_out_kernel<<<(E / 4 + 255) / 256, 256, 0, stream>>>(ei, pk,
                                                             out_ew, out_em,
                                                             nodemask, E);
    node_mask_kernel<<<(N / 4 + 255) / 256, 256, 0, stream>>>(nodemask, out_nmask, N);
}

// Round 15
// 211.787 us; speedup vs baseline: 1.3130x; 1.0048x over previous
//
#include <hip/hip_runtime.h>
#include <hip/hip_bf16.h>

#define HID 256
#define HID2 512
#define NPG 200
#define LN_EPS 1e-5f

typedef float f32x4 __attribute__((ext_vector_type(4)));
typedef float f32x2 __attribute__((ext_vector_type(2)));
typedef short s16x8 __attribute__((ext_vector_type(8)));
typedef unsigned short ushort_t;

// round-to-nearest-even float -> bf16 bit pattern
__device__ __forceinline__ ushort_t f2bf_rne(float x) {
    union { float f; unsigned int u; } c; c.f = x;
    unsigned int u = c.u;
    return (ushort_t)((u + 0x7fffu + ((u >> 16) & 1u)) >> 16);
}
__device__ __forceinline__ float bf2f(ushort_t h) {
    union { unsigned int u; float f; } c; c.u = ((unsigned int)h) << 16;
    return c.f;
}

// ---------------------------------------------------------------------------
// K_w1: W1[256][512] -> fragment-major bf16 hi/lo buffers.
// ---------------------------------------------------------------------------
__global__ __launch_bounds__(256)
void w1_prep_kernel(const float* __restrict__ W1,
                    ushort_t* __restrict__ w1h, ushort_t* __restrict__ w1l)
{
    const int col = blockIdx.x;    // 0..511
    const int k   = threadIdx.x;   // 0..255
    const float v = W1[(size_t)k * HID2 + col];
    const ushort_t hi = f2bf_rne(v);
    const ushort_t lo = f2bf_rne(v - bf2f(hi));
    const int tile = col >> 4, lc = col & 15;
    const int kq = k >> 5, gq = (k >> 3) & 3, j = k & 7;
    const size_t idx = ((((size_t)tile << 3) + kq) * 64 + (gq << 4) + lc) * 8 + j;
    w1h[idx] = hi;
    w1l[idx] = lo;
}

// ---------------------------------------------------------------------------
// K1: fused  x = h + g[batch];  z = x@W1 + b1;  LayerNorm; ReLU; logit = z.W2+b2
// bf16x3 MFMA, fully-unrolled STATIC K-loop, BM=32. kq=0 B-fragments peeled
// to before staging (hides first L2 trip under the staging phase).
// Plateau ledger (measured): time invariant BM{32,64}; regfile caps 4
// waves/SIMD; runtime-dependent K offsets spill (r9/r11) — keep static.
// ---------------------------------------------------------------------------
__global__ __launch_bounds__(512, 4)
void mlp_logits_mfma(const float* __restrict__ h, const float* __restrict__ g,
                     const int* __restrict__ batch,
                     const ushort_t* __restrict__ w1h, const ushort_t* __restrict__ w1l,
                     const float* __restrict__ b1,
                     const float* __restrict__ lng, const float* __restrict__ lnb,
                     const float* __restrict__ W2, const float* __restrict__ b2,
                     float* __restrict__ logits)
{
    __shared__ ushort_t xsh[32 * 256];   // 16 KB, swizzled
    __shared__ ushort_t xsl[32 * 256];   // 16 KB, swizzled
    __shared__ float prm[4 * 512];       // b1 | lng | lnb | W2 (8 KB)
    __shared__ float redS1[8][32];
    __shared__ float redS2[8][32];
    __shared__ float redT[8][32];
    __shared__ float muv[32], rsv[32];

    const int tid  = threadIdx.x;
    const int row0 = blockIdx.x * 32;

    const int w  = tid >> 6;       // wave 0..7 -> cols w*64..+63
    const int l  = tid & 63;
    const int lc = l & 15;         // A-row / B-col / C-col index within tile
    const int gq = l >> 4;         // k-chunk group 0..3 (and C row group)
    const int wcol0 = w << 6;

    // fragment-major B base for this wave+lane: tiles w*4..w*4+3
    const ushort_t* bfh = w1h + (((size_t)w << 2) << 3) * 512 + (size_t)l * 8;
    const ushort_t* bfl = w1l + (((size_t)w << 2) << 3) * 512 + (size_t)l * 8;

    // ---- early-issue kq=0 B fragments (independent of staging) ----
    s16x8 bh0[4], bl0[4];
    #pragma unroll
    for (int ct = 0; ct < 4; ++ct) {
        const size_t foff = (size_t)(ct << 3) * 512;
        bh0[ct] = *reinterpret_cast<const s16x8*>(bfh + foff);
        bl0[ct] = *reinterpret_cast<const s16x8*>(bfl + foff);
    }

    // ---- params -> LDS ----
    {
        const int c = tid;               // 0..511
        prm[c]        = b1[c];
        prm[512 + c]  = lng[c];
        prm[1024 + c] = lnb[c];
        prm[1536 + c] = W2[c];
    }

    // ---- stage x = h + g[batch], split to bf16 hi/lo in swizzled LDS ----
    #pragma unroll
    for (int i = 0; i < 2; ++i) {
        const int ci = tid + (i << 9);      // 0..1023
        const int r  = ci >> 5;             // 0..31
        const int kc = (ci & 31) << 3;      // 0..248
        const int grow = row0 + r;
        const int gb   = batch[grow];
        const f32x4* hp = reinterpret_cast<const f32x4*>(h + (size_t)grow * HID + kc);
        const f32x4* gp = reinterpret_cast<const f32x4*>(g + (size_t)gb   * HID + kc);
        const f32x4 h0 = __builtin_nontemporal_load(hp);
        const f32x4 h1 = __builtin_nontemporal_load(hp + 1);
        const f32x4 g0 = gp[0], g1 = gp[1];
        float xv[8] = { h0.x + g0.x, h0.y + g0.y, h0.z + g0.z, h0.w + g0.w,
                        h1.x + g1.x, h1.y + g1.y, h1.z + g1.z, h1.w + g1.w };
        ushort_t hh[8], ll[8];
        #pragma unroll
        for (int j = 0; j < 8; ++j) {
            const ushort_t hi = f2bf_rne(xv[j]);
            hh[j] = hi;
            ll[j] = f2bf_rne(xv[j] - bf2f(hi));
        }
        int byte_off = r * 512 + (kc << 1);
        byte_off ^= (r & 7) << 4;
        *reinterpret_cast<s16x8*>(reinterpret_cast<char*>(xsh) + byte_off) =
            *reinterpret_cast<const s16x8*>(hh);
        *reinterpret_cast<s16x8*>(reinterpret_cast<char*>(xsl) + byte_off) =
            *reinterpret_cast<const s16x8*>(ll);
    }
    __syncthreads();

    f32x4 acc[2][4];               // [rt][ct]
    #pragma unroll
    for (int rt = 0; rt < 2; ++rt)
        #pragma unroll
        for (int ct = 0; ct < 4; ++ct) acc[rt][ct] = (f32x4){0.f, 0.f, 0.f, 0.f};

    #pragma unroll
    for (int kq = 0; kq < 8; ++kq) {
        s16x8 bh[4], bl[4];
        #pragma unroll
        for (int ct = 0; ct < 4; ++ct) {
            if (kq == 0) {                 // constant-folded: peeled prefetch
                bh[ct] = bh0[ct];
                bl[ct] = bl0[ct];
            } else {
                const size_t foff = (size_t)((ct << 3) + kq) * 512;
                bh[ct] = *reinterpret_cast<const s16x8*>(bfh + foff);
                bl[ct] = *reinterpret_cast<const s16x8*>(bfl + foff);
            }
        }
        s16x8 ah[2], al[2];
        #pragma unroll
        for (int rt = 0; rt < 2; ++rt) {
            const int arow = (rt << 4) | lc;
            int abyte = arow * 512 + (((kq << 5) + (gq << 3)) << 1);
            abyte ^= (arow & 7) << 4;
            ah[rt] = *reinterpret_cast<const s16x8*>(
                         reinterpret_cast<const char*>(xsh) + abyte);
            al[rt] = *reinterpret_cast<const s16x8*>(
                         reinterpret_cast<const char*>(xsl) + abyte);
        }
        #pragma unroll
        for (int ct = 0; ct < 4; ++ct)
            #pragma unroll
            for (int rt = 0; rt < 2; ++rt)
                acc[rt][ct] = __builtin_amdgcn_mfma_f32_16x16x32_bf16(ah[rt], bh[ct], acc[rt][ct], 0, 0, 0);
        #pragma unroll
        for (int ct = 0; ct < 4; ++ct)
            #pragma unroll
            for (int rt = 0; rt < 2; ++rt)
                acc[rt][ct] = __builtin_amdgcn_mfma_f32_16x16x32_bf16(al[rt], bh[ct], acc[rt][ct], 0, 0, 0);
        #pragma unroll
        for (int ct = 0; ct < 4; ++ct)
            #pragma unroll
            for (int rt = 0; rt < 2; ++rt)
                acc[rt][ct] = __builtin_amdgcn_mfma_f32_16x16x32_bf16(ah[rt], bl[ct], acc[rt][ct], 0, 0, 0);
    }

    // ---- epilogue ----
    #pragma unroll
    for (int rt = 0; rt < 2; ++rt) {
        float s1[4] = {0.f, 0.f, 0.f, 0.f};
        float s2[4] = {0.f, 0.f, 0.f, 0.f};
        #pragma unroll
        for (int ct = 0; ct < 4; ++ct) {
            const float bb = prm[wcol0 + (ct << 4) + lc];
            #pragma unroll
            for (int reg = 0; reg < 4; ++reg) {
                const float v = acc[rt][ct][reg] + bb;
                acc[rt][ct][reg] = v;
                s1[reg] += v;
                s2[reg] = fmaf(v, v, s2[reg]);
            }
        }
        #pragma unroll
        for (int reg = 0; reg < 4; ++reg) {
            float a = s1[reg], q = s2[reg];
            a += __shfl_xor(a, 1); q += __shfl_xor(q, 1);
            a += __shfl_xor(a, 2); q += __shfl_xor(q, 2);
            a += __shfl_xor(a, 4); q += __shfl_xor(q, 4);
            a += __shfl_xor(a, 8); q += __shfl_xor(q, 8);
            if (lc == 0) {
                const int row = (rt << 4) + (gq << 2) + reg;
                redS1[w][row] = a;
                redS2[w][row] = q;
            }
        }
    }
    __syncthreads();

    if (tid < 32) {
        float S1 = 0.f, S2 = 0.f;
        #pragma unroll
        for (int i = 0; i < 8; ++i) { S1 += redS1[i][tid]; S2 += redS2[i][tid]; }
        const float mu = S1 * (1.0f / HID2);
        const float var = S2 * (1.0f / HID2) - mu * mu;
        muv[tid] = mu;
        rsv[tid] = rsqrtf(var + LN_EPS);
    }
    __syncthreads();

    #pragma unroll
    for (int rt = 0; rt < 2; ++rt) {
        float tpart[4] = {0.f, 0.f, 0.f, 0.f};
        float mus[4], rss[4];
        #pragma unroll
        for (int reg = 0; reg < 4; ++reg) {
            const int row = (rt << 4) + (gq << 2) + reg;
            mus[reg] = muv[row];
            rss[reg] = rsv[row];
        }
        #pragma unroll
        for (int ct = 0; ct < 4; ++ct) {
            const int c = wcol0 + (ct << 4) + lc;
            const float lg = prm[512 + c], lb = prm[1024 + c], w2 = prm[1536 + c];
            #pragma unroll
            for (int reg = 0; reg < 4; ++reg) {
                float zn = (acc[rt][ct][reg] - mus[reg]) * rss[reg] * lg + lb;
                zn = fmaxf(zn, 0.f);
                tpart[reg] = fmaf(zn, w2, tpart[reg]);
            }
        }
        #pragma unroll
        for (int reg = 0; reg < 4; ++reg) {
            float t = tpart[reg];
            t += __shfl_xor(t, 1); t += __shfl_xor(t, 2);
            t += __shfl_xor(t, 4); t += __shfl_xor(t, 8);
            if (lc == 0) redT[w][(rt << 4) + (gq << 2) + reg] = t;
        }
    }
    __syncthreads();

    if (tid < 32) {
        float t = 0.f;
        #pragma unroll
        for (int i = 0; i < 8; ++i) t += redT[i][tid];
        logits[row0 + tid] = t + b2[0];
    }
}

// ---------------------------------------------------------------------------
// K2: per-graph softmax + seed selection; zeroes this graph's nm/nodemask.
// ---------------------------------------------------------------------------
__global__ __launch_bounds__(256)
void softmax_seed_kernel(const float* __restrict__ logits,
                         float* __restrict__ out_prob,
                         unsigned char* __restrict__ nm,
                         unsigned char* __restrict__ nodemask)
{
    const int gid  = blockIdx.x;
    const int tid  = threadIdx.x;
    const int node = gid * NPG + tid;
    const bool act = tid < NPG;

    if (tid < NPG / 4) {
        reinterpret_cast<unsigned int*>(nm + gid * NPG)[tid] = 0u;
        reinterpret_cast<unsigned int*>(nodemask + gid * NPG)[tid] = 0u;
    }

    __shared__ float redf[4];
    __shared__ int   redi[4];

    float l = act ? logits[node] : -INFINITY;

    float m = l;
    #pragma unroll
    for (int off = 32; off >= 1; off >>= 1) m = fmaxf(m, __shfl_xor(m, off));
    if ((tid & 63) == 0) redf[tid >> 6] = m;
    __syncthreads();
    const float bm = fmaxf(fmaxf(redf[0], redf[1]), fmaxf(redf[2], redf[3]));
    __syncthreads();

    const float e = act ? expf(l - bm) : 0.0f;
    float s = e;
    #pragma unroll
    for (int off = 32; off >= 1; off >>= 1) s += __shfl_xor(s, off);
    if ((tid & 63) == 0) redf[tid >> 6] = s;
    __syncthreads();
    const float bs = redf[0] + redf[1] + redf[2] + redf[3];
    __syncthreads();

    const float p = act ? e / bs : -1.0f;
    if (act) out_prob[node] = p;

    float pm = p;
    #pragma unroll
    for (int off = 32; off >= 1; off >>= 1) pm = fmaxf(pm, __shfl_xor(pm, off));
    if ((tid & 63) == 0) redf[tid >> 6] = pm;
    __syncthreads();
    const float bpm = fmaxf(fmaxf(redf[0], redf[1]), fmaxf(redf[2], redf[3]));

    int c = (act && p >= bpm) ? node : 0x7FFFFFFF;
    #pragma unroll
    for (int off = 32; off >= 1; off >>= 1) c = min(c, __shfl_xor(c, off));
    if ((tid & 63) == 0) redi[tid >> 6] = c;
    __syncthreads();
    if (tid == 0) {
        const int seed = min(min(redi[0], redi[1]), min(redi[2], redi[3]));
        nm[seed] = 1;   // level 1
    }
}

// ---------------------------------------------------------------------------
// K3/K4: one synchronous BFS hop (expand target -> source), level-tagged.
// ---------------------------------------------------------------------------
__global__ __launch_bounds__(256)
void bfs_pass_kernel(const int* __restrict__ ei, unsigned char* __restrict__ nm,
                     const int E, const int maxlvl, const int newlvl)
{
    const int e = (blockIdx.x * blockDim.x + threadIdx.x) << 2;
    if (e >= E) return;
    const int4 d4 = *reinterpret_cast<const int4*>(ei + E + e);
    #pragma unroll
    for (int j = 0; j < 4; ++j) {
        const int d = (j == 0) ? d4.x : (j == 1) ? d4.y : (j == 2) ? d4.z : d4.w;
        const int lv = nm[d];
        if (lv >= 1 && lv <= maxlvl) {
            const int s = ei[e + j];
            if (nm[s] == 0) nm[s] = (unsigned char)newlvl;
        }
    }
}

// ---------------------------------------------------------------------------
// K4b: pack {logit, nm-flag} into 8B entries (halves edge_out's gather count).
// ---------------------------------------------------------------------------
__global__ __launch_bounds__(256)
void pack_kernel(const float* __restrict__ logits,
                 const unsigned char* __restrict__ nm,
                 f32x2* __restrict__ pk, const int N)
{
    const int i = blockIdx.x * blockDim.x + threadIdx.x;
    if (i < N) {
        f32x2 v;
        v.x = logits[i];
        v.y = nm[i] ? 1.0f : 0.0f;
        pk[i] = v;
    }
}

// ---------------------------------------------------------------------------
// K5: edge outputs + node-mask scatter, 4 edges/thread, packed 8B gathers.
// ---------------------------------------------------------------------------
__global__ __launch_bounds__(256)
void edge_out_kernel(const int* __restrict__ ei, const f32x2* __restrict__ pk,
                     float* __restrict__ out_ew,
                     float* __restrict__ out_em,
                     unsigned char* __restrict__ nodemask, const int E)
{
    const int e = (blockIdx.x * blockDim.x + threadIdx.x) << 2;
    if (e >= E) return;
    const int4 s4 = *reinterpret_cast<const int4*>(ei + e);
    const int4 d4 = *reinterpret_cast<const int4*>(ei + E + e);
    f32x4 ew, em;
    #pragma unroll
    for (int j = 0; j < 4; ++j) {
        const int s = (j == 0) ? s4.x : (j == 1) ? s4.y : (j == 2) ? s4.z : s4.w;
        const int d = (j == 0) ? d4.x : (j == 1) ? d4.y : (j == 2) ? d4.z : d4.w;
        const f32x2 ps = pk[s];
        const f32x2 pd = pk[d];
        ew[j] = ps.x + pd.x;
        const bool m = (ps.y != 0.0f) && (pd.y != 0.0f);
        em[j] = m ? 1.0f : 0.0f;
        if (m) { nodemask[s] = 1; nodemask[d] = 1; }
    }
    *reinterpret_cast<f32x4*>(out_ew + e) = ew;
    *reinterpret_cast<f32x4*>(out_em + e) = em;
}

// ---------------------------------------------------------------------------
// K6: node_mask -> float32 output, 4 nodes/thread.
// ---------------------------------------------------------------------------
__global__ __launch_bounds__(256)
void node_mask_kernel(const unsigned char* __restrict__ nodemask,
                      float* __restrict__ out_nm, const int N)
{
    const int i = (blockIdx.x * blockDim.x + threadIdx.x) << 2;
    if (i >= N) return;
    const uchar4 m4 = *reinterpret_cast<const uchar4*>(nodemask + i);
    f32x4 o;
    o[0] = m4.x ? 1.0f : 0.0f;
    o[1] = m4.y ? 1.0f : 0.0f;
    o[2] = m4.z ? 1.0f : 0.0f;
    o[3] = m4.w ? 1.0f : 0.0f;
    *reinterpret_cast<f32x4*>(out_nm + i) = o;
}

extern "C" void kernel_launch(void* const* d_in, const int* in_sizes, int n_in,
                              void* d_out, int out_size, void* d_ws, size_t ws_size,
                              hipStream_t stream)
{
    const float* h     = (const float*)d_in[0];
    const float* g     = (const float*)d_in[1];
    const int*   batch = (const int*)d_in[2];
    const int*   ei    = (const int*)d_in[3];
    const float* W1    = (const float*)d_in[4];
    const float* b1    = (const float*)d_in[5];
    const float* lng   = (const float*)d_in[6];
    const float* lnb   = (const float*)d_in[7];
    const float* W2    = (const float*)d_in[8];
    const float* b2    = (const float*)d_in[9];

    const int N = in_sizes[2];
    const int E = in_sizes[3] / 2;

    float* out        = (float*)d_out;
    float* out_prob   = out;                                  // [N]
    float* out_ew     = out + N;                              // [E]
    float* out_em     = out + (size_t)N + E;                  // [E]
    float* out_nmask  = out + (size_t)N + 2 * (size_t)E;      // [N]

    // workspace layout
    char* ws = (char*)d_ws;
    float*         logits   = (float*)ws;                                // N*4
    ushort_t*      w1h      = (ushort_t*)(ws + (size_t)N * 4);           // 256 KB
    ushort_t*      w1l      = (ushort_t*)(ws + (size_t)N * 4 + 262144);  // 256 KB
    unsigned char* nm       = (unsigned char*)(ws + (size_t)N * 4 + 524288);
    unsigned char* nodemask = nm + N;
    f32x2*         pk       = (f32x2*)(ws + (size_t)N * 4 + 524288 + 2 * (size_t)N);

    w1_prep_kernel<<<HID2, HID, 0, stream>>>(W1, w1h, w1l);

    mlp_logits_mfma<<<N / 32, 512, 0, stream>>>(h, g, batch, w1h, w1l,
                                                b1, lng, lnb, W2, b2, logits);
    softmax_seed_kernel<<<N / NPG, 256, 0, stream>>>(logits, out_prob, nm, nodemask);
    bfs_pass_kernel<<<(E / 4 + 255) / 256, 256, 0, stream>>>(ei, nm, E, 1, 2);
    bfs_pass_kernel<<<(E / 4 + 255) / 256, 256, 0, stream>>>(ei, nm, E, 2, 3);
    pack_kernel<<<(N + 255) / 256, 256, 0, stream>>>(logits, nm, pk, N);
    edge_out_kernel<<<(E / 4 + 255) / 256, 256, 0, stream>>>(ei, pk,
                                                             out_ew, out_em,
                                                             nodemask, E);
    node_mask_kernel<<<(N / 4 + 255) / 256, 256, 0, stream>>>(nodemask, out_nmask, N);
}

// Round 16
// 211.349 us; speedup vs baseline: 1.3157x; 1.0021x over previous
//
#include <hip/hip_runtime.h>
#include <hip/hip_bf16.h>

#define HID 256
#define HID2 512
#define NPG 200
#define LN_EPS 1e-5f

typedef float f32x4 __attribute__((ext_vector_type(4)));
typedef float f32x2 __attribute__((ext_vector_type(2)));
typedef short s16x8 __attribute__((ext_vector_type(8)));
typedef unsigned short ushort_t;

// round-to-nearest-even float -> bf16 bit pattern
__device__ __forceinline__ ushort_t f2bf_rne(float x) {
    union { float f; unsigned int u; } c; c.f = x;
    unsigned int u = c.u;
    return (ushort_t)((u + 0x7fffu + ((u >> 16) & 1u)) >> 16);
}
__device__ __forceinline__ float bf2f(ushort_t h) {
    union { unsigned int u; float f; } c; c.u = ((unsigned int)h) << 16;
    return c.f;
}

// ---------------------------------------------------------------------------
// K_w1: W1[256][512] -> fragment-major bf16 hi/lo buffers.
// ---------------------------------------------------------------------------
__global__ __launch_bounds__(256)
void w1_prep_kernel(const float* __restrict__ W1,
                    ushort_t* __restrict__ w1h, ushort_t* __restrict__ w1l)
{
    const int col = blockIdx.x;    // 0..511
    const int k   = threadIdx.x;   // 0..255
    const float v = W1[(size_t)k * HID2 + col];
    const ushort_t hi = f2bf_rne(v);
    const ushort_t lo = f2bf_rne(v - bf2f(hi));
    const int tile = col >> 4, lc = col & 15;
    const int kq = k >> 5, gq = (k >> 3) & 3, j = k & 7;
    const size_t idx = ((((size_t)tile << 3) + kq) * 64 + (gq << 4) + lc) * 8 + j;
    w1h[idx] = hi;
    w1l[idx] = lo;
}

// ---------------------------------------------------------------------------
// K1: fused  x = h + g[batch];  z = x@W1 + b1;  LayerNorm; ReLU; logit = z.W2+b2
// bf16x3 MFMA, BM=32, STATIC one-deep B double-buffer: B(kq+1) issued at the
// top of step kq via macro-expanded named even/odd buffers (all indices
// compile-time -> rule-#20-safe, unlike r9's lambda / r11's rotation).
// Spill check: WRITE_SIZE must stay ~400KB.
// ---------------------------------------------------------------------------
#define KQ_STEP(KQ, BHC, BHN, BLC, BLN)                                       \
    {                                                                         \
        if ((KQ) < 7) {                                                       \
            _Pragma("unroll")                                                 \
            for (int ct = 0; ct < 4; ++ct) {                                  \
                const size_t fo = (size_t)((ct << 3) + (KQ) + 1) * 512;       \
                BHN[ct] = *reinterpret_cast<const s16x8*>(bfh + fo);          \
                BLN[ct] = *reinterpret_cast<const s16x8*>(bfl + fo);          \
            }                                                                 \
        }                                                                     \
        s16x8 ah_[2], al_[2];                                                 \
        _Pragma("unroll")                                                     \
        for (int rt = 0; rt < 2; ++rt) {                                      \
            const int arow = (rt << 4) | lc;                                  \
            int abyte = arow * 512 + ((((KQ) << 5) + (gq << 3)) << 1);        \
            abyte ^= (arow & 7) << 4;                                         \
            ah_[rt] = *reinterpret_cast<const s16x8*>(                        \
                          reinterpret_cast<const char*>(xsh) + abyte);        \
            al_[rt] = *reinterpret_cast<const s16x8*>(                        \
                          reinterpret_cast<const char*>(xsl) + abyte);        \
        }                                                                     \
        _Pragma("unroll")                                                     \
        for (int ct = 0; ct < 4; ++ct)                                        \
            _Pragma("unroll")                                                 \
            for (int rt = 0; rt < 2; ++rt)                                    \
                acc[rt][ct] = __builtin_amdgcn_mfma_f32_16x16x32_bf16(        \
                                  ah_[rt], BHC[ct], acc[rt][ct], 0, 0, 0);    \
        _Pragma("unroll")                                                     \
        for (int ct = 0; ct < 4; ++ct)                                        \
            _Pragma("unroll")                                                 \
            for (int rt = 0; rt < 2; ++rt)                                    \
                acc[rt][ct] = __builtin_amdgcn_mfma_f32_16x16x32_bf16(        \
                                  al_[rt], BHC[ct], acc[rt][ct], 0, 0, 0);    \
        _Pragma("unroll")                                                     \
        for (int ct = 0; ct < 4; ++ct)                                        \
            _Pragma("unroll")                                                 \
            for (int rt = 0; rt < 2; ++rt)                                    \
                acc[rt][ct] = __builtin_amdgcn_mfma_f32_16x16x32_bf16(        \
                                  ah_[rt], BLC[ct], acc[rt][ct], 0, 0, 0);    \
    }

__global__ __launch_bounds__(512, 4)
void mlp_logits_mfma(const float* __restrict__ h, const float* __restrict__ g,
                     const int* __restrict__ batch,
                     const ushort_t* __restrict__ w1h, const ushort_t* __restrict__ w1l,
                     const float* __restrict__ b1,
                     const float* __restrict__ lng, const float* __restrict__ lnb,
                     const float* __restrict__ W2, const float* __restrict__ b2,
                     float* __restrict__ logits)
{
    __shared__ ushort_t xsh[32 * 256];   // 16 KB, swizzled
    __shared__ ushort_t xsl[32 * 256];   // 16 KB, swizzled
    __shared__ float prm[4 * 512];       // b1 | lng | lnb | W2 (8 KB)
    __shared__ float redS1[8][32];
    __shared__ float redS2[8][32];
    __shared__ float redT[8][32];
    __shared__ float muv[32], rsv[32];

    const int tid  = threadIdx.x;
    const int row0 = blockIdx.x * 32;

    const int w  = tid >> 6;       // wave 0..7 -> cols w*64..+63
    const int l  = tid & 63;
    const int lc = l & 15;         // A-row / B-col / C-col index within tile
    const int gq = l >> 4;         // k-chunk group 0..3 (and C row group)
    const int wcol0 = w << 6;

    // fragment-major B base for this wave+lane: tiles w*4..w*4+3
    const ushort_t* bfh = w1h + (((size_t)w << 2) << 3) * 512 + (size_t)l * 8;
    const ushort_t* bfl = w1l + (((size_t)w << 2) << 3) * 512 + (size_t)l * 8;

    // ---- early-issue kq=0 B fragments (independent of staging) ----
    s16x8 bhA[4], bhB[4], blA[4], blB[4];
    #pragma unroll
    for (int ct = 0; ct < 4; ++ct) {
        const size_t foff = (size_t)(ct << 3) * 512;
        bhA[ct] = *reinterpret_cast<const s16x8*>(bfh + foff);
        blA[ct] = *reinterpret_cast<const s16x8*>(bfl + foff);
    }

    // ---- params -> LDS ----
    {
        const int c = tid;               // 0..511
        prm[c]        = b1[c];
        prm[512 + c]  = lng[c];
        prm[1024 + c] = lnb[c];
        prm[1536 + c] = W2[c];
    }

    // ---- stage x = h + g[batch], split to bf16 hi/lo in swizzled LDS ----
    #pragma unroll
    for (int i = 0; i < 2; ++i) {
        const int ci = tid + (i << 9);      // 0..1023
        const int r  = ci >> 5;             // 0..31
        const int kc = (ci & 31) << 3;      // 0..248
        const int grow = row0 + r;
        const int gb   = batch[grow];
        const f32x4* hp = reinterpret_cast<const f32x4*>(h + (size_t)grow * HID + kc);
        const f32x4* gp = reinterpret_cast<const f32x4*>(g + (size_t)gb   * HID + kc);
        const f32x4 h0 = __builtin_nontemporal_load(hp);
        const f32x4 h1 = __builtin_nontemporal_load(hp + 1);
        const f32x4 g0 = gp[0], g1 = gp[1];
        float xv[8] = { h0.x + g0.x, h0.y + g0.y, h0.z + g0.z, h0.w + g0.w,
                        h1.x + g1.x, h1.y + g1.y, h1.z + g1.z, h1.w + g1.w };
        ushort_t hh[8], ll[8];
        #pragma unroll
        for (int j = 0; j < 8; ++j) {
            const ushort_t hi = f2bf_rne(xv[j]);
            hh[j] = hi;
            ll[j] = f2bf_rne(xv[j] - bf2f(hi));
        }
        int byte_off = r * 512 + (kc << 1);
        byte_off ^= (r & 7) << 4;
        *reinterpret_cast<s16x8*>(reinterpret_cast<char*>(xsh) + byte_off) =
            *reinterpret_cast<const s16x8*>(hh);
        *reinterpret_cast<s16x8*>(reinterpret_cast<char*>(xsl) + byte_off) =
            *reinterpret_cast<const s16x8*>(ll);
    }
    __syncthreads();

    f32x4 acc[2][4];               // [rt][ct]
    #pragma unroll
    for (int rt = 0; rt < 2; ++rt)
        #pragma unroll
        for (int ct = 0; ct < 4; ++ct) acc[rt][ct] = (f32x4){0.f, 0.f, 0.f, 0.f};

    // ---- K loop: 8 static steps, alternating named B buffers ----
    KQ_STEP(0, bhA, bhB, blA, blB)
    KQ_STEP(1, bhB, bhA, blB, blA)
    KQ_STEP(2, bhA, bhB, blA, blB)
    KQ_STEP(3, bhB, bhA, blB, blA)
    KQ_STEP(4, bhA, bhB, blA, blB)
    KQ_STEP(5, bhB, bhA, blB, blA)
    KQ_STEP(6, bhA, bhB, blA, blB)
    KQ_STEP(7, bhB, bhA, blB, blA)

    // ---- epilogue ----
    #pragma unroll
    for (int rt = 0; rt < 2; ++rt) {
        float s1[4] = {0.f, 0.f, 0.f, 0.f};
        float s2[4] = {0.f, 0.f, 0.f, 0.f};
        #pragma unroll
        for (int ct = 0; ct < 4; ++ct) {
            const float bb = prm[wcol0 + (ct << 4) + lc];
            #pragma unroll
            for (int reg = 0; reg < 4; ++reg) {
                const float v = acc[rt][ct][reg] + bb;
                acc[rt][ct][reg] = v;
                s1[reg] += v;
                s2[reg] = fmaf(v, v, s2[reg]);
            }
        }
        #pragma unroll
        for (int reg = 0; reg < 4; ++reg) {
            float a = s1[reg], q = s2[reg];
            a += __shfl_xor(a, 1); q += __shfl_xor(q, 1);
            a += __shfl_xor(a, 2); q += __shfl_xor(q, 2);
            a += __shfl_xor(a, 4); q += __shfl_xor(q, 4);
            a += __shfl_xor(a, 8); q += __shfl_xor(q, 8);
            if (lc == 0) {
                const int row = (rt << 4) + (gq << 2) + reg;
                redS1[w][row] = a;
                redS2[w][row] = q;
            }
        }
    }
    __syncthreads();

    if (tid < 32) {
        float S1 = 0.f, S2 = 0.f;
        #pragma unroll
        for (int i = 0; i < 8; ++i) { S1 += redS1[i][tid]; S2 += redS2[i][tid]; }
        const float mu = S1 * (1.0f / HID2);
        const float var = S2 * (1.0f / HID2) - mu * mu;
        muv[tid] = mu;
        rsv[tid] = rsqrtf(var + LN_EPS);
    }
    __syncthreads();

    #pragma unroll
    for (int rt = 0; rt < 2; ++rt) {
        float tpart[4] = {0.f, 0.f, 0.f, 0.f};
        float mus[4], rss[4];
        #pragma unroll
        for (int reg = 0; reg < 4; ++reg) {
            const int row = (rt << 4) + (gq << 2) + reg;
            mus[reg] = muv[row];
            rss[reg] = rsv[row];
        }
        #pragma unroll
        for (int ct = 0; ct < 4; ++ct) {
            const int c = wcol0 + (ct << 4) + lc;
            const float lg = prm[512 + c], lb = prm[1024 + c], w2 = prm[1536 + c];
            #pragma unroll
            for (int reg = 0; reg < 4; ++reg) {
                float zn = (acc[rt][ct][reg] - mus[reg]) * rss[reg] * lg + lb;
                zn = fmaxf(zn, 0.f);
                tpart[reg] = fmaf(zn, w2, tpart[reg]);
            }
        }
        #pragma unroll
        for (int reg = 0; reg < 4; ++reg) {
            float t = tpart[reg];
            t += __shfl_xor(t, 1); t += __shfl_xor(t, 2);
            t += __shfl_xor(t, 4); t += __shfl_xor(t, 8);
            if (lc == 0) redT[w][(rt << 4) + (gq << 2) + reg] = t;
        }
    }
    __syncthreads();

    if (tid < 32) {
        float t = 0.f;
        #pragma unroll
        for (int i = 0; i < 8; ++i) t += redT[i][tid];
        logits[row0 + tid] = t + b2[0];
    }
}

// ---------------------------------------------------------------------------
// K2: per-graph softmax + seed selection; zeroes this graph's nm/nodemask.
// ---------------------------------------------------------------------------
__global__ __launch_bounds__(256)
void softmax_seed_kernel(const float* __restrict__ logits,
                         float* __restrict__ out_prob,
                         unsigned char* __restrict__ nm,
                         unsigned char* __restrict__ nodemask)
{
    const int gid  = blockIdx.x;
    const int tid  = threadIdx.x;
    const int node = gid * NPG + tid;
    const bool act = tid < NPG;

    if (tid < NPG / 4) {
        reinterpret_cast<unsigned int*>(nm + gid * NPG)[tid] = 0u;
        reinterpret_cast<unsigned int*>(nodemask + gid * NPG)[tid] = 0u;
    }

    __shared__ float redf[4];
    __shared__ int   redi[4];

    float l = act ? logits[node] : -INFINITY;

    float m = l;
    #pragma unroll
    for (int off = 32; off >= 1; off >>= 1) m = fmaxf(m, __shfl_xor(m, off));
    if ((tid & 63) == 0) redf[tid >> 6] = m;
    __syncthreads();
    const float bm = fmaxf(fmaxf(redf[0], redf[1]), fmaxf(redf[2], redf[3]));
    __syncthreads();

    const float e = act ? expf(l - bm) : 0.0f;
    float s = e;
    #pragma unroll
    for (int off = 32; off >= 1; off >>= 1) s += __shfl_xor(s, off);
    if ((tid & 63) == 0) redf[tid >> 6] = s;
    __syncthreads();
    const float bs = redf[0] + redf[1] + redf[2] + redf[3];
    __syncthreads();

    const float p = act ? e / bs : -1.0f;
    if (act) out_prob[node] = p;

    float pm = p;
    #pragma unroll
    for (int off = 32; off >= 1; off >>= 1) pm = fmaxf(pm, __shfl_xor(pm, off));
    if ((tid & 63) == 0) redf[tid >> 6] = pm;
    __syncthreads();
    const float bpm = fmaxf(fmaxf(redf[0], redf[1]), fmaxf(redf[2], redf[3]));

    int c = (act && p >= bpm) ? node : 0x7FFFFFFF;
    #pragma unroll
    for (int off = 32; off >= 1; off >>= 1) c = min(c, __shfl_xor(c, off));
    if ((tid & 63) == 0) redi[tid >> 6] = c;
    __syncthreads();
    if (tid == 0) {
        const int seed = min(min(redi[0], redi[1]), min(redi[2], redi[3]));
        nm[seed] = 1;   // level 1
    }
}

// ---------------------------------------------------------------------------
// K3/K4: one synchronous BFS hop (expand target -> source), level-tagged.
// ---------------------------------------------------------------------------
__global__ __launch_bounds__(256)
void bfs_pass_kernel(const int* __restrict__ ei, unsigned char* __restrict__ nm,
                     const int E, const int maxlvl, const int newlvl)
{
    const int e = (blockIdx.x * blockDim.x + threadIdx.x) << 2;
    if (e >= E) return;
    const int4 d4 = *reinterpret_cast<const int4*>(ei + E + e);
    #pragma unroll
    for (int j = 0; j < 4; ++j) {
        const int d = (j == 0) ? d4.x : (j == 1) ? d4.y : (j == 2) ? d4.z : d4.w;
        const int lv = nm[d];
        if (lv >= 1 && lv <= maxlvl) {
            const int s = ei[e + j];
            if (nm[s] == 0) nm[s] = (unsigned char)newlvl;
        }
    }
}

// ---------------------------------------------------------------------------
// K4b: pack {logit, nm-flag} into 8B entries (halves edge_out's gather count).
// ---------------------------------------------------------------------------
__global__ __launch_bounds__(256)
void pack_kernel(const float* __restrict__ logits,
                 const unsigned char* __restrict__ nm,
                 f32x2* __restrict__ pk, const int N)
{
    const int i = blockIdx.x * blockDim.x + threadIdx.x;
    if (i < N) {
        f32x2 v;
        v.x = logits[i];
        v.y = nm[i] ? 1.0f : 0.0f;
        pk[i] = v;
    }
}

// ---------------------------------------------------------------------------
// K5: edge outputs + node-mask scatter, 4 edges/thread, packed 8B gathers.
// ---------------------------------------------------------------------------
__global__ __launch_bounds__(256)
void edge_out_kernel(const int* __restrict__ ei, const f32x2* __restrict__ pk,
                     float* __restrict__ out_ew,
                     float* __restrict__ out_em,
                     unsigned char* __restrict__ nodemask, const int E)
{
    const int e = (blockIdx.x * blockDim.x + threadIdx.x) << 2;
    if (e >= E) return;
    const int4 s4 = *reinterpret_cast<const int4*>(ei + e);
    const int4 d4 = *reinterpret_cast<const int4*>(ei + E + e);
    f32x4 ew, em;
    #pragma unroll
    for (int j = 0; j < 4; ++j) {
        const int s = (j == 0) ? s4.x : (j == 1) ? s4.y : (j == 2) ? s4.z : s4.w;
        const int d = (j == 0) ? d4.x : (j == 1) ? d4.y : (j == 2) ? d4.z : d4.w;
        const f32x2 ps = pk[s];
        const f32x2 pd = pk[d];
        ew[j] = ps.x + pd.x;
        const bool m = (ps.y != 0.0f) && (pd.y != 0.0f);
        em[j] = m ? 1.0f : 0.0f;
        if (m) { nodemask[s] = 1; nodemask[d] = 1; }
    }
    *reinterpret_cast<f32x4*>(out_ew + e) = ew;
    *reinterpret_cast<f32x4*>(out_em + e) = em;
}

// ---------------------------------------------------------------------------
// K6: node_mask -> float32 output, 4 nodes/thread.
// ---------------------------------------------------------------------------
__global__ __launch_bounds__(256)
void node_mask_kernel(const unsigned char* __restrict__ nodemask,
                      float* __restrict__ out_nm, const int N)
{
    const int i = (blockIdx.x * blockDim.x + threadIdx.x) << 2;
    if (i >= N) return;
    const uchar4 m4 = *reinterpret_cast<const uchar4*>(nodemask + i);
    f32x4 o;
    o[0] = m4.x ? 1.0f : 0.0f;
    o[1] = m4.y ? 1.0f : 0.0f;
    o[2] = m4.z ? 1.0f : 0.0f;
    o[3] = m4.w ? 1.0f : 0.0f;
    *reinterpret_cast<f32x4*>(out_nm + i) = o;
}

extern "C" void kernel_launch(void* const* d_in, const int* in_sizes, int n_in,
                              void* d_out, int out_size, void* d_ws, size_t ws_size,
                              hipStream_t stream)
{
    const float* h     = (const float*)d_in[0];
    const float* g     = (const float*)d_in[1];
    const int*   batch = (const int*)d_in[2];
    const int*   ei    = (const int*)d_in[3];
    const float* W1    = (const float*)d_in[4];
    const float* b1    = (const float*)d_in[5];
    const float* lng   = (const float*)d_in[6];
    const float* lnb   = (const float*)d_in[7];
    const float* W2    = (const float*)d_in[8];
    const float* b2    = (const float*)d_in[9];

    const int N = in_sizes[2];
    const int E = in_sizes[3] / 2;

    float* out        = (float*)d_out;
    float* out_prob   = out;                                  // [N]
    float* out_ew     = out + N;                              // [E]
    float* out_em     = out + (size_t)N + E;                  // [E]
    float* out_nmask  = out + (size_t)N + 2 * (size_t)E;      // [N]

    // workspace layout
    char* ws = (char*)d_ws;
    float*         logits   = (float*)ws;                                // N*4
    ushort_t*      w1h      = (ushort_t*)(ws + (size_t)N * 4);           // 256 KB
    ushort_t*      w1l      = (ushort_t*)(ws + (size_t)N * 4 + 262144);  // 256 KB
    unsigned char* nm       = (unsigned char*)(ws + (size_t)N * 4 + 524288);
    unsigned char* nodemask = nm + N;
    f32x2*         pk       = (f32x2*)(ws + (size_t)N * 4 + 524288 + 2 * (size_t)N);

    w1_prep_kernel<<<HID2, HID, 0, stream>>>(W1, w1h, w1l);

    mlp_logits_mfma<<<N / 32, 512, 0, stream>>>(h, g, batch, w1h, w1l,
                                                b1, lng, lnb, W2, b2, logits);
    softmax_seed_kernel<<<N / NPG, 256, 0, stream>>>(logits, out_prob, nm, nodemask);
    bfs_pass_kernel<<<(E / 4 + 255) / 256, 256, 0, stream>>>(ei, nm, E, 1, 2);
    bfs_pass_kernel<<<(E / 4 + 255) / 256, 256, 0, stream>>>(ei, nm, E, 2, 3);
    pack_kernel<<<(N + 255) / 256, 256, 0, stream>>>(logits, nm, pk, N);
    edge_out_kernel<<<(E / 4 + 255) / 256, 256, 0, stream>>>(ei, pk,
                                                             out_ew, out_em,
                                                             nodemask, E);
    node_mask_kernel<<<(N / 4 + 255) / 256, 256, 0, stream>>>(nodemask, out_nmask, N);
}